// Round 10
// baseline (873.363 us; speedup 1.0000x reference)
//
#include <hip/hip_runtime.h>

typedef __attribute__((ext_vector_type(8))) short bf16x8;
typedef __attribute__((ext_vector_type(4))) short s16x4;
typedef __attribute__((ext_vector_type(4))) float f32x4;

__device__ __forceinline__ float fsig(float x){ return 1.0f/(1.0f + __expf(-x)); }
__device__ __forceinline__ float ftanh(float x){
  x = fminf(fmaxf(x, -15.f), 15.f);
  float e = __expf(2.f*x);
  return (e - 1.f)/(e + 1.f);
}

__device__ __forceinline__ short f2bf(float x){
  union { float f; unsigned u; } v; v.f = x;
  unsigned r = v.u + 0x7fffu + ((v.u >> 16) & 1u);
  return (short)(r >> 16);
}

// Slot barrier for 256 blocks: block i stores phase to slots[i] (agent
// write-through); wave 0 polls 4 slots/lane. Callers must have made all
// cross-block visible stores with agent-scope atomic stores (drained by the
// s_waitcnt(0) here before signaling). Acquire = agent fence (invalidate).
__device__ __forceinline__ void treebarS(int* slots, int* phase){
  asm volatile("" ::: "memory");
  __builtin_amdgcn_s_waitcnt(0);
  asm volatile("" ::: "memory");
  __syncthreads();
  int ph = *phase + 1;
  if (threadIdx.x == 0)
    __hip_atomic_store(&slots[blockIdx.x], ph, __ATOMIC_RELAXED, __HIP_MEMORY_SCOPE_AGENT);
  if (threadIdx.x < 64){
    int base = threadIdx.x << 2;
    int spins = 0;
    for (;;){
      int a = __hip_atomic_load(&slots[base+0], __ATOMIC_RELAXED, __HIP_MEMORY_SCOPE_AGENT);
      int b = __hip_atomic_load(&slots[base+1], __ATOMIC_RELAXED, __HIP_MEMORY_SCOPE_AGENT);
      int c = __hip_atomic_load(&slots[base+2], __ATOMIC_RELAXED, __HIP_MEMORY_SCOPE_AGENT);
      int d = __hip_atomic_load(&slots[base+3], __ATOMIC_RELAXED, __HIP_MEMORY_SCOPE_AGENT);
      int mn = min(min(a,b), min(c,d));
      if (__all(mn >= ph)) break;
      if (++spins > 128) __builtin_amdgcn_s_sleep(1);
    }
    __builtin_amdgcn_fence(__ATOMIC_ACQUIRE, "agent");
  }
  __syncthreads();
  (*phase)++;
}

// ---------------- k_rank: 4 emb rows per block, LDS-staged coalesced w1.
// Block 256 is the zero-duty block (merged former k_zero).
__global__ __launch_bounds__(128) void k_rank(const float* __restrict__ emb,
                                              const float* __restrict__ w1,
                                              const float* __restrict__ w2,
                                              float* __restrict__ SC,
                                              short* __restrict__ HG,
                                              int* __restrict__ LEVCNT,
                                              int* __restrict__ MAXLEV,
                                              int* __restrict__ NODECNT,
                                              int* __restrict__ BAR1,
                                              int* __restrict__ GRP){
  if (blockIdx.x == 256){
    int tid = threadIdx.x;
    for (int i = tid; i < 32768; i += 128) HG[i] = 0;
    if (tid < 64) LEVCNT[tid] = 0;
    if (tid == 64) MAXLEV[0] = 0;
    if (tid == 65) NODECNT[0] = 0;
    if (tid >= 66 && tid < 98) BAR1[tid - 66] = 0;
    GRP[tid] = 0; GRP[tid + 128] = 0;
    return;
  }
  __shared__ float WT[128][65];
  __shared__ float ES[4][64];
  __shared__ float red[4][128];
  int tid = threadIdx.x;
  int bl0 = blockIdx.x * 4;
  float acc0 = 0.f, acc1 = 0.f, acc2 = 0.f, acc3 = 0.f;
  for (int k0 = 0; k0 < 1024; k0 += 64){
    __syncthreads();
    #pragma unroll
    for (int it = 0; it < 16; it++){
      int idx = it*128 + tid;
      int rw = idx >> 4, c4 = (idx & 15) * 4;
      float4 v = *(const float4*)(w1 + rw*1024 + k0 + c4);
      WT[rw][c4+0] = v.x; WT[rw][c4+1] = v.y; WT[rw][c4+2] = v.z; WT[rw][c4+3] = v.w;
    }
    if (tid < 64){
      int r = tid >> 4, c4 = (tid & 15) * 4;
      float4 v = *(const float4*)(emb + (bl0 + r)*1024 + k0 + c4);
      ES[r][c4+0] = v.x; ES[r][c4+1] = v.y; ES[r][c4+2] = v.z; ES[r][c4+3] = v.w;
    }
    __syncthreads();
    #pragma unroll
    for (int c = 0; c < 64; c++){
      float wv = WT[tid][c];
      acc0 += wv * ES[0][c];
      acc1 += wv * ES[1][c];
      acc2 += wv * ES[2][c];
      acc3 += wv * ES[3][c];
    }
  }
  float w2v = w2[tid];
  red[0][tid] = fmaxf(acc0, 0.f) * w2v;
  red[1][tid] = fmaxf(acc1, 0.f) * w2v;
  red[2][tid] = fmaxf(acc2, 0.f) * w2v;
  red[3][tid] = fmaxf(acc3, 0.f) * w2v;
  __syncthreads();
  for (int st = 64; st > 0; st >>= 1){
    if (tid < st){
      red[0][tid] += red[0][tid + st];
      red[1][tid] += red[1][tid + st];
      red[2][tid] += red[2][tid + st];
      red[3][tid] += red[3][tid + st];
    }
    __syncthreads();
  }
  if (tid < 4) SC[bl0 + tid] = red[tid][0];
}

// ---------------- k_gx (MFMA bf16): GX[bl][r] = emb[bl]·w_ih[r] + b_ih[r] + b_hh[r]
__global__ __launch_bounds__(256) void k_gx(const float* __restrict__ emb,
                                            const float* __restrict__ w_ih,
                                            const float* __restrict__ b_ih,
                                            const float* __restrict__ b_hh,
                                            float* __restrict__ GX){
  __shared__ short Ws[64][72];
  __shared__ short Es[64][72];
  int mt = blockIdx.x >> 4;
  int nt4 = blockIdx.x & 15;
  int r0 = mt*64, n0 = nt4*64;
  int lane = threadIdx.x & 63, w = threadIdx.x >> 6;
  int m16 = lane & 15, quad = lane >> 4;
  int srr = threadIdx.x >> 2, skk = (threadIdx.x & 3)*16;
  f32x4 acc[4] = {{0,0,0,0},{0,0,0,0},{0,0,0,0},{0,0,0,0}};
  for (int k0 = 0; k0 < 1024; k0 += 64){
    #pragma unroll
    for (int i = 0; i < 4; i++){
      float4 v = *(const float4*)(w_ih + (r0 + srr)*1024 + k0 + skk + i*4);
      s16x4 wv; wv[0] = f2bf(v.x); wv[1] = f2bf(v.y); wv[2] = f2bf(v.z); wv[3] = f2bf(v.w);
      *(s16x4*)&Ws[srr][skk + i*4] = wv;
      float4 u = *(const float4*)(emb + (n0 + srr)*1024 + k0 + skk + i*4);
      s16x4 ev; ev[0] = f2bf(u.x); ev[1] = f2bf(u.y); ev[2] = f2bf(u.z); ev[3] = f2bf(u.w);
      *(s16x4*)&Es[srr][skk + i*4] = ev;
    }
    __syncthreads();
    #pragma unroll
    for (int ks = 0; ks < 64; ks += 32){
      bf16x8 a = *(bf16x8*)&Ws[w*16 + m16][ks + quad*8];
      #pragma unroll
      for (int nt = 0; nt < 4; nt++){
        bf16x8 b = *(bf16x8*)&Es[nt*16 + m16][ks + quad*8];
        acc[nt] = __builtin_amdgcn_mfma_f32_16x16x32_bf16(a, b, acc[nt], 0, 0, 0);
      }
    }
    __syncthreads();
  }
  int rbase = r0 + w*16 + quad*4;
  f32x4 bi = *(const f32x4*)(b_ih + rbase);
  f32x4 bh = *(const f32x4*)(b_hh + rbase);
  #pragma unroll
  for (int nt = 0; nt < 4; nt++){
    int n = n0 + nt*16 + m16;
    f32x4 o = acc[nt] + bi + bh;
    *(f32x4*)(GX + n*4096 + rbase) = o;
  }
}

// ---------------- k_build: wave-parallel tree build, batched atomics
__global__ __launch_bounds__(64) void k_build(const float* __restrict__ SC,
      const int* __restrict__ length,
      int* __restrict__ LCH, int* __restrict__ RCH, int* __restrict__ ISNODE,
      int* __restrict__ LEVCNT, int* __restrict__ LEVLIST, int* __restrict__ LEVEID,
      int* __restrict__ EINFO, int* __restrict__ PARENTREF, int* __restrict__ NODECNT,
      int* __restrict__ ROOTP, int* __restrict__ MAXLEV, float* __restrict__ OUT){
  __shared__ int stk_s[64], stk_e[64], stk_p[64];
  __shared__ int order_l[64], ns_l[64], ne_l[64];
  __shared__ int lch_l[64], rch_l[64], isn_l[64], lev_l[64];
  __shared__ int par_l[64], seg_l[64], eid_l[64];
  __shared__ int hist[64], hbase[64], hrk[64];
  int b = blockIdx.x;
  int q = threadIdx.x;
  float sc_q = SC[b*64 + q];
  isn_l[q] = 0; hist[q] = 0; hrk[q] = 0; lch_l[q] = -1; rch_l[q] = -1;
  __syncthreads();
  int len = length[b];
  int cnt = 0, sp = 0;
  if (len >= 2){ stk_s[0] = 0; stk_e[0] = len; stk_p[0] = -1; sp = 1; }
  // All 64 lanes execute this loop with uniform control flow; stack writes are
  // uniform-value same-address (each lane sees its own write).
  while (sp > 0){
    sp--;
    int s = stk_s[sp], e = stk_e[sp], pp = stk_p[sp];
    float val = (q >= s && q < e) ? sc_q : -1e30f;
    int idx = q;
    #pragma unroll
    for (int st = 32; st > 0; st >>= 1){
      float ov = __shfl_xor(val, st, 64);
      int   oi = __shfl_xor(idx, st, 64);
      if (ov > val || (ov == val && oi < idx)){ val = ov; idx = oi; }  // first-max tie-break
    }
    int pos = idx;  // uniform
    order_l[cnt] = pos; ns_l[pos] = s; ne_l[pos] = e; isn_l[pos] = 1;
    if (pp >= 0){
      int ppos = pp >> 1, side = pp & 1;
      if (side) rch_l[ppos] = pos; else lch_l[ppos] = pos;
      par_l[pos] = ppos; seg_l[pos] = side;
    } else par_l[pos] = -1;
    int ll = pos - s, rl = e - pos - 1;
    if (ll == 1) lch_l[pos] = s;
    else if (ll >= 2){ stk_s[sp] = s; stk_e[sp] = pos; stk_p[sp] = pos << 1; sp++; }
    if (rl == 1) rch_l[pos] = pos + 1;
    else if (rl >= 2){ stk_s[sp] = pos + 1; stk_e[sp] = e; stk_p[sp] = (pos << 1) | 1; sp++; }
    cnt++;
  }
  // level assignment (children appear after parent in order => reverse pass)
  for (int i = cnt - 1; i >= 0; i--){
    int p = order_l[i];
    int lv = 0;
    int lq = lch_l[p];
    if (lq >= 0 && isn_l[lq]) lv = lev_l[lq] + 1;
    int rq = rch_l[p];
    if (rq >= 0 && isn_l[rq] && lev_l[rq] + 1 > lv) lv = lev_l[rq] + 1;
    lev_l[p] = lv;
  }
  __syncthreads();
  if (q < cnt) atomicAdd(&hist[lev_l[order_l[q]]], 1);
  __syncthreads();
  int ebase0 = 0;
  if (q == 0 && cnt > 0) ebase0 = atomicAdd(NODECNT, cnt);
  ebase0 = __shfl(ebase0, 0, 64);
  if (hist[q] > 0) hbase[q] = atomicAdd(&LEVCNT[q], hist[q]);  // one parallel round
  __syncthreads();
  if (q < cnt){
    int p = order_l[q];
    int lv = lev_l[p];
    int slot = hbase[lv] + atomicAdd(&hrk[lv], 1);
    int eid = ebase0 + q;
    eid_l[p] = eid;
    LEVLIST[lv*512 + slot] = (b << 8) | p;
    LEVEID[lv*512 + slot]  = eid;
    EINFO[eid] = (b << 8) | p;
  }
  __syncthreads();
  if (q < cnt){
    int p = order_l[q];
    PARENTREF[ebase0 + q] = (par_l[p] >= 0) ? (eid_l[par_l[p]]*2 + seg_l[p]) : -1;
  }
  LCH[b*64 + q] = lch_l[q];
  RCH[b*64 + q] = rch_l[q];
  ISNODE[b*64 + q] = isn_l[q];
  if (q == 0){
    ROOTP[b] = (cnt > 0) ? order_l[0] : 0;
    if (cnt > 0) atomicMax(MAXLEV, lev_l[order_l[0]]);
  }
  // REINFORCE log-prob terms, wave-parallel per node
  float lp = 0.f;
  for (int i = 0; i < cnt; i++){
    int p = order_l[i], s = ns_l[p], e = ne_l[p];
    bool in = (q >= s && q < e);
    float v = in ? sc_q : -1e30f;
    #pragma unroll
    for (int st = 32; st > 0; st >>= 1) v = fmaxf(v, __shfl_xor(v, st, 64));
    float ex = in ? expf(sc_q - v) : 0.f;
    #pragma unroll
    for (int st = 32; st > 0; st >>= 1) ex += __shfl_xor(ex, st, 64);
    float scp = __shfl(sc_q, p, 64);
    lp += (float)(e - s) * (scp - (v + logf(ex)));
  }
  if (q == 0) OUT[32768 + b] = lp;
}

// ---------------- k_lstm (cooperative, 32 blocks x 512) — round-7 known-good.
__global__ __launch_bounds__(512, 2) void k_lstm(const float* __restrict__ w_hh,
      const float* __restrict__ GX, float* __restrict__ HS, float* __restrict__ CS,
      short* __restrict__ HG, int* __restrict__ SLOTS){
  __shared__ float EX[4][32][17];
  __shared__ short HGs[16384];     // 32 KB staged h (bf16, [ch>>3][batch][ch&7])
  int bi = blockIdx.x;
  int w = threadIdx.x >> 6, lane = threadIdx.x & 63;
  int quad = lane >> 4, m16 = lane & 15;
  int gate = w >> 1, jhalf = w & 1;
  int j0 = bi*32;
  int row = gate*1024 + j0 + jhalf*16 + m16;
  bf16x8 Wf[32];
  #pragma unroll
  for (int ks = 0; ks < 32; ks++){
    const float* p = w_hh + row*1024 + ks*32 + quad*8;
    float4 a = *(const float4*)p;
    float4 b = *(const float4*)(p + 4);
    bf16x8 o;
    o[0]=f2bf(a.x); o[1]=f2bf(a.y); o[2]=f2bf(a.z); o[3]=f2bf(a.w);
    o[4]=f2bf(b.x); o[5]=f2bf(b.y); o[6]=f2bf(b.z); o[7]=f2bf(b.w);
    Wf[ks] = o;
  }
  int tid = threadIdx.x;
  int ojl = tid & 31;        // channel-in-block (coalescing remap)
  int ob  = tid >> 5;        // batch
  int oj = j0 + ojl;
  float creg = 0.f;
  int jloc_base = jhalf*16 + quad*4;
  int phase = 0;
  const float* gxp = GX + ob*64*4096 + oj;
  float4 pg, pg2;
  pg.x = gxp[0]; pg.y = gxp[1024]; pg.z = gxp[2048]; pg.w = gxp[3072];
  for (int t = 0; t < 64; t++){
    const short* HR = HG + (t & 1)*16384;
    short* HW = HG + ((t + 1) & 1)*16384;
    f32x4 acc = {0.f,0.f,0.f,0.f};
    f32x4 a1 = {0.f,0.f,0.f,0.f}, a2 = {0.f,0.f,0.f,0.f}, a3 = {0.f,0.f,0.f,0.f};
    if (t > 0){
      // issue all 4 granule loads (consecutive lanes -> consecutive 16B)
      float4 s0 = *(const float4*)(HR + (0*512 + tid)*8);
      float4 s1 = *(const float4*)(HR + (1*512 + tid)*8);
      float4 s2 = *(const float4*)(HR + (2*512 + tid)*8);
      float4 s3 = *(const float4*)(HR + (3*512 + tid)*8);
      if (t < 63){   // next-step gx prefetch rides with stage loads
        const float* g2 = gxp + (t + 1)*4096;
        pg2.x = g2[0]; pg2.y = g2[1024]; pg2.z = g2[2048]; pg2.w = g2[3072];
      }
      // half 1 (channels 0..511 -> HGs bytes < 16KB)
      *(float4*)&HGs[(0*512 + tid)*8] = s0;
      *(float4*)&HGs[(1*512 + tid)*8] = s1;
      __syncthreads();
      #pragma unroll
      for (int ks = 0; ks < 16; ks += 4){
        bf16x8 b0 = *(const bf16x8*)&HGs[(ks*4     + quad)*128 + m16*8];
        bf16x8 b1 = *(const bf16x8*)&HGs[((ks+1)*4 + quad)*128 + m16*8];
        bf16x8 b2 = *(const bf16x8*)&HGs[((ks+2)*4 + quad)*128 + m16*8];
        bf16x8 b3 = *(const bf16x8*)&HGs[((ks+3)*4 + quad)*128 + m16*8];
        acc = __builtin_amdgcn_mfma_f32_16x16x32_bf16(Wf[ks],   b0, acc, 0, 0, 0);
        a1  = __builtin_amdgcn_mfma_f32_16x16x32_bf16(Wf[ks+1], b1, a1,  0, 0, 0);
        a2  = __builtin_amdgcn_mfma_f32_16x16x32_bf16(Wf[ks+2], b2, a2,  0, 0, 0);
        a3  = __builtin_amdgcn_mfma_f32_16x16x32_bf16(Wf[ks+3], b3, a3,  0, 0, 0);
      }
      // half 2 (channels 512..1023 -> HGs bytes >= 16KB; loads landed under MFMA)
      *(float4*)&HGs[(2*512 + tid)*8] = s2;
      *(float4*)&HGs[(3*512 + tid)*8] = s3;
      __syncthreads();
      #pragma unroll
      for (int ks = 16; ks < 32; ks += 4){
        bf16x8 b0 = *(const bf16x8*)&HGs[(ks*4     + quad)*128 + m16*8];
        bf16x8 b1 = *(const bf16x8*)&HGs[((ks+1)*4 + quad)*128 + m16*8];
        bf16x8 b2 = *(const bf16x8*)&HGs[((ks+2)*4 + quad)*128 + m16*8];
        bf16x8 b3 = *(const bf16x8*)&HGs[((ks+3)*4 + quad)*128 + m16*8];
        acc = __builtin_amdgcn_mfma_f32_16x16x32_bf16(Wf[ks],   b0, acc, 0, 0, 0);
        a1  = __builtin_amdgcn_mfma_f32_16x16x32_bf16(Wf[ks+1], b1, a1,  0, 0, 0);
        a2  = __builtin_amdgcn_mfma_f32_16x16x32_bf16(Wf[ks+2], b2, a2,  0, 0, 0);
        a3  = __builtin_amdgcn_mfma_f32_16x16x32_bf16(Wf[ks+3], b3, a3,  0, 0, 0);
      }
      acc = (acc + a1) + (a2 + a3);
      // (no barrier needed here: next HGs write is >=2 barriers away)
    } else {
      if (t < 63){
        const float* g2 = gxp + (t + 1)*4096;
        pg2.x = g2[0]; pg2.y = g2[1024]; pg2.z = g2[2048]; pg2.w = g2[3072];
      }
    }
    #pragma unroll
    for (int r = 0; r < 4; r++) EX[gate][jloc_base + r][m16] = acc[r];
    __syncthreads();
    float gi = EX[0][ojl][ob] + pg.x;
    float gf = EX[1][ojl][ob] + pg.y;
    float gu = EX[2][ojl][ob] + pg.z;
    float go = EX[3][ojl][ob] + pg.w;
    float cc = fsig(gf)*creg + fsig(gi)*ftanh(gu);
    float hh = fsig(go)*ftanh(cc);
    creg = cc;
    __hip_atomic_store(&HW[(oj >> 3)*128 + ob*8 + (oj & 7)], f2bf(hh),
                       __ATOMIC_RELAXED, __HIP_MEMORY_SCOPE_AGENT);
    if (t < 63){
      pg = pg2;
      asm volatile("" ::: "memory");
      __builtin_amdgcn_s_waitcnt(0);   // drains HW store (stage/prefetch already done)
      asm volatile("" ::: "memory");
      __syncthreads();
      // result stores issued here stay in flight during the spin (coalesced)
      HS[(ob*64 + t)*1024 + oj] = hh;
      CS[(ob*64 + t)*1024 + oj] = cc;
      int ph = phase + 1;
      if (tid == 0)
        __hip_atomic_store(&SLOTS[bi], ph, __ATOMIC_RELAXED, __HIP_MEMORY_SCOPE_AGENT);
      if (tid < 64){
        int spins = 0;
        for (;;){
          int v = __hip_atomic_load(&SLOTS[lane & 31], __ATOMIC_RELAXED, __HIP_MEMORY_SCOPE_AGENT);
          if (__all(v >= ph)) break;
          if (++spins > 128) __builtin_amdgcn_s_sleep(1);
        }
        __builtin_amdgcn_fence(__ATOMIC_ACQUIRE, "agent");
      }
      __syncthreads();
      phase = ph;
    } else {
      HS[(ob*64 + t)*1024 + oj] = hh;
      CS[(ob*64 + t)*1024 + oj] = cc;
    }
  }
}

// ---------------- k_tree3 (cooperative, 256 blocks x 512 — 8 waves)
// Round-9 structure with the kc chunk loop FULLY UNROLLED: the rolled loop's
// loop-carried buf[] forced a vmcnt(0) drain per chunk (VGPR stuck at 52 ->
// ~96 serialized L2 round trips per tile, the r9 latency bound). Straight-line
// SSA lets the scheduler hoist loads across chunks under the 256-VGPR budget
// of __launch_bounds__(512,2).
__global__ __launch_bounds__(512, 2) void k_tree3(const float* __restrict__ tl_w,
      const float* __restrict__ tl_b,
      float* __restrict__ HS, float* __restrict__ CS,
      const int* __restrict__ LCH, const int* __restrict__ RCH,
      const int* __restrict__ ISNODE,
      const int* __restrict__ LEVCNT, const int* __restrict__ LEVLIST,
      const int* __restrict__ LEVEID, const int* __restrict__ EINFO,
      const int* __restrict__ PARENTREF, const int* __restrict__ NODECNT,
      const int* __restrict__ MAXLEV, short* __restrict__ HCAT,
      const int* __restrict__ ROOTP, float* __restrict__ OUT,
      int* __restrict__ SLOTS){
  extern __shared__ short WL[];                 // 24 rows x 3080 shorts
  float* EXF = (float*)(WL + 24*3080);          // 8 waves x 400 floats
  int bi = blockIdx.x;
  int J0 = bi*4;
  for (int gidx = threadIdx.x; gidx < 24*384; gidx += 512){
    int ri = gidx / 384;
    int col = (gidx % 384)*8;
    int g = ri >> 2, c = ri & 3;
    const float* p = tl_w + (g*1024 + J0 + c)*3072 + col;
    float4 a = *(const float4*)p;
    float4 b2 = *(const float4*)(p + 4);
    bf16x8 o;
    o[0]=f2bf(a.x); o[1]=f2bf(a.y); o[2]=f2bf(a.z); o[3]=f2bf(a.w);
    o[4]=f2bf(b2.x); o[5]=f2bf(b2.y); o[6]=f2bf(b2.z); o[7]=f2bf(b2.w);
    *(bf16x8*)&WL[ri*3080 + col] = o;
  }
  int lane = threadIdx.x & 63, w = threadIdx.x >> 6;
  int m16 = lane & 15, quad = lane >> 4;
  int uj = J0 + quad;                 // this lane's update channel
  float tb[6];
  #pragma unroll
  for (int g = 0; g < 6; g++) tb[g] = tl_b[g*1024 + uj];
  __syncthreads();
  int phase = 0;
  // prefill HCAT (m-seg = leaf h; leaf/absent child segs)
  int ncnt = NODECNT[0];
  {
    int total = ncnt * 1024;
    for (int idx = bi*512 + threadIdx.x; idx < total; idx += 131072){
      int eid = idx >> 10, j = idx & 1023;
      int e = EINFO[eid]; int b = e >> 8, p = e & 255;
      __hip_atomic_store(&HCAT[eid*3072 + 2048 + j], f2bf(HS[(b*64 + p)*1024 + j]),
                         __ATOMIC_RELAXED, __HIP_MEMORY_SCOPE_AGENT);
      int lq = LCH[b*64 + p];
      if (lq < 0)
        __hip_atomic_store(&HCAT[eid*3072 + j], (short)0, __ATOMIC_RELAXED, __HIP_MEMORY_SCOPE_AGENT);
      else if (!ISNODE[b*64 + lq])
        __hip_atomic_store(&HCAT[eid*3072 + j], f2bf(HS[(b*64 + lq)*1024 + j]),
                           __ATOMIC_RELAXED, __HIP_MEMORY_SCOPE_AGENT);
      int rq = RCH[b*64 + p];
      if (rq < 0)
        __hip_atomic_store(&HCAT[eid*3072 + 1024 + j], (short)0, __ATOMIC_RELAXED, __HIP_MEMORY_SCOPE_AGENT);
      else if (!ISNODE[b*64 + rq])
        __hip_atomic_store(&HCAT[eid*3072 + 1024 + j], f2bf(HS[(b*64 + rq)*1024 + j]),
                           __ATOMIC_RELAXED, __HIP_MEMORY_SCOPE_AGENT);
    }
  }
  treebarS(SLOTS, &phase);
  int maxlev = MAXLEV[0];
  for (int v = 0; v <= maxlev; v++){
    int nc = LEVCNT[v];
    int ntiles = (nc + 15) >> 4;
    for (int nt = w; nt < ntiles; nt += 8){
      int n = nt*16 + m16;
      bool valid = (n < nc);
      int eid = valid ? LEVEID[v*512 + n] : 1023;
      int e   = valid ? LEVLIST[v*512 + n] : 0;
      int b = e >> 8, p = e & 255;
      int lq = valid ? LCH[b*64 + p] : -1;
      int rq = valid ? RCH[b*64 + p] : -1;
      int pr = valid ? PARENTREF[eid] : -1;
      float cl = (valid && lq >= 0) ? CS[(b*64 + lq)*1024 + uj] : 0.f;
      float cr = (valid && rq >= 0) ? CS[(b*64 + rq)*1024 + uj] : 0.f;
      float cm = valid ? CS[(b*64 + p)*1024 + uj] : 0.f;
      const short* bp  = HCAT + eid*3072 + quad*8;
      const short* a0p = WL + m16*3080 + quad*8;
      const short* a1p = WL + (16 + (m16 & 7))*3080 + quad*8;
      f32x4 acc0 = {0,0,0,0}, acc1 = {0,0,0,0};
      // fully-unrolled software-pipelined K-loop: 12 chunks x 8 k-steps in
      // straight-line SSA; loads for chunk kc+1 are issued before chunk kc's
      // MFMAs, and the scheduler can keep many in flight (no loop-carried
      // register array, no per-chunk vmcnt(0) drain).
      bf16x8 buf[8];
      #pragma unroll
      for (int i = 0; i < 8; i++) buf[i] = *(const bf16x8*)(bp + i*32);
      #pragma unroll
      for (int kc = 0; kc < 12; kc++){
        bf16x8 cur[8];
        #pragma unroll
        for (int i = 0; i < 8; i++) cur[i] = buf[i];
        if (kc < 11){
          const short* nxt = bp + (kc + 1)*256;
          #pragma unroll
          for (int i = 0; i < 8; i++) buf[i] = *(const bf16x8*)(nxt + i*32);
        }
        int kb = kc*256;
        #pragma unroll
        for (int i = 0; i < 8; i++){
          int k0 = kb + i*32;
          bf16x8 a0 = *(const bf16x8*)(a0p + k0);
          bf16x8 a1 = *(const bf16x8*)(a1p + k0);
          acc0 = __builtin_amdgcn_mfma_f32_16x16x32_bf16(a0, cur[i], acc0, 0, 0, 0);
          acc1 = __builtin_amdgcn_mfma_f32_16x16x32_bf16(a1, cur[i], acc1, 0, 0, 0);
        }
      }
      // in-wave gate exchange: D row quad*4+r of acc0 = ri (g*4+c) 0..15;
      // acc1 rows map to ri 16+((quad*4+r)&7) (quads 2,3 duplicate 0,1)
      float* ex = EXF + w*400;
      #pragma unroll
      for (int r = 0; r < 4; r++) ex[m16*25 + quad*4 + r] = acc0[r];
      if (quad < 2){
        #pragma unroll
        for (int r = 0; r < 4; r++) ex[m16*25 + 16 + quad*4 + r] = acc1[r];
      }
      // update: lane = (node m16, channel quad)
      if (valid){
        float gv[6];
        #pragma unroll
        for (int g = 0; g < 6; g++) gv[g] = ex[m16*25 + g*4 + quad] + tb[g];
        float c = fsig(gv[1])*cl + fsig(gv[2])*cr + fsig(gv[3])*cm + fsig(gv[0])*ftanh(gv[4]);
        float h = fsig(gv[5])*ftanh(c);
        __hip_atomic_store(&HS[(b*64 + p)*1024 + uj], h, __ATOMIC_RELAXED, __HIP_MEMORY_SCOPE_AGENT);
        __hip_atomic_store(&CS[(b*64 + p)*1024 + uj], c, __ATOMIC_RELAXED, __HIP_MEMORY_SCOPE_AGENT);
        if (pr >= 0)
          __hip_atomic_store(&HCAT[(pr >> 1)*3072 + (pr & 1)*1024 + uj], f2bf(h),
                             __ATOMIC_RELAXED, __HIP_MEMORY_SCOPE_AGENT);
      }
    }
    treebarS(SLOTS, &phase);
  }
  // fused root gather
  for (int idx = bi*512 + threadIdx.x; idx < 32768; idx += 131072){
    int half = idx >> 14;
    int b = (idx >> 10) & 15, j = idx & 1023;
    int rp = ROOTP[b];
    OUT[half*16384 + b*1024 + j] = half ? CS[(b*64 + rp)*1024 + j]
                                        : HS[(b*64 + rp)*1024 + j];
  }
}

extern "C" void kernel_launch(void* const* d_in, const int* in_sizes, int n_in,
                              void* d_out, int out_size, void* d_ws, size_t ws_size,
                              hipStream_t stream) {
  (void)in_sizes; (void)n_in; (void)out_size; (void)ws_size;
  const float* emb    = (const float*)d_in[0];
  const int*   length = (const int*)  d_in[2];
  const float* w_ih   = (const float*)d_in[3];
  const float* w_hh   = (const float*)d_in[4];
  const float* b_ih   = (const float*)d_in[5];
  const float* b_hh   = (const float*)d_in[6];
  const float* tl_w   = (const float*)d_in[7];
  const float* tl_b   = (const float*)d_in[8];
  const float* rk_w1  = (const float*)d_in[9];
  const float* rk_w2  = (const float*)d_in[10];
  float* OUT = (float*)d_out;

  float* ws_f = (float*)d_ws;
  float* GX   = ws_f;                        // 4,194,304 f
  float* HS   = ws_f + 4194304;              // 1,048,576 f
  float* CS   = ws_f + 5242880;              // 1,048,576 f
  short* HCAT = (short*)(ws_f + 6291456);    // 1024*3072 shorts
  float* SC   = ws_f + 7864320;              // 1,024 f
  short* HG   = (short*)(ws_f + 7865344);    // 32,768 shorts
  int*   IW   = (int*)(ws_f + 7881728);
  int* LCH      = IW;               // 1024
  int* RCH      = IW + 1024;        // 1024
  int* ISNODE   = IW + 2048;        // 1024
  int* LEVCNT   = IW + 3072;        // 64
  int* LEVLIST  = IW + 3136;        // 32768
  int* LEVEID   = IW + 35904;       // 32768
  int* EINFO    = IW + 68672;       // 1024
  int* PARENTREF= IW + 69696;       // 1024
  int* ROOTP    = IW + 70720;       // 16
  int* MAXLEV   = IW + 70736;
  int* NODECNT  = IW + 70737;
  int* BAR1     = IW + 70752;       // 32 slots (k_lstm barrier)
  int* GRP      = IW + 70784;       // 256 slots (k_tree3 barrier)

  k_rank<<<257, 128, 0, stream>>>(emb, rk_w1, rk_w2, SC, HG, LEVCNT, MAXLEV,
                                  NODECNT, BAR1, GRP);
  k_gx<<<1024, 256, 0, stream>>>(emb, w_ih, b_ih, b_hh, GX);
  k_build<<<16, 64, 0, stream>>>(SC, length, LCH, RCH, ISNODE, LEVCNT, LEVLIST,
                                 LEVEID, EINFO, PARENTREF, NODECNT, ROOTP, MAXLEV, OUT);

  {
    void* args[] = { (void*)&w_hh, (void*)&GX, (void*)&HS, (void*)&CS, (void*)&HG,
                     (void*)&BAR1 };
    hipLaunchCooperativeKernel((const void*)k_lstm, dim3(32), dim3(512), args, 0, stream);
  }
  {
    hipFuncSetAttribute((const void*)k_tree3,
                        hipFuncAttributeMaxDynamicSharedMemorySize, 160640);
    void* args[] = { (void*)&tl_w, (void*)&tl_b, (void*)&HS, (void*)&CS,
                     (void*)&LCH, (void*)&RCH, (void*)&ISNODE,
                     (void*)&LEVCNT, (void*)&LEVLIST, (void*)&LEVEID, (void*)&EINFO,
                     (void*)&PARENTREF, (void*)&NODECNT, (void*)&MAXLEV,
                     (void*)&HCAT, (void*)&ROOTP, (void*)&OUT,
                     (void*)&GRP };
    hipLaunchCooperativeKernel((const void*)k_tree3, dim3(256), dim3(512), args,
                               160640, stream);
  }
}

// Round 11
// 825.276 us; speedup vs baseline: 1.0583x; 1.0583x over previous
//
#include <hip/hip_runtime.h>

typedef __attribute__((ext_vector_type(8))) short bf16x8;
typedef __attribute__((ext_vector_type(4))) short s16x4;
typedef __attribute__((ext_vector_type(4))) float f32x4;
typedef __attribute__((ext_vector_type(4))) int i32x4;

__device__ __forceinline__ float fsig(float x){ return 1.0f/(1.0f + __expf(-x)); }
__device__ __forceinline__ float ftanh(float x){
  x = fminf(fmaxf(x, -15.f), 15.f);
  float e = __expf(2.f*x);
  return (e - 1.f)/(e + 1.f);
}

__device__ __forceinline__ short f2bf(float x){
  union { float f; unsigned u; } v; v.f = x;
  unsigned r = v.u + 0x7fffu + ((v.u >> 16) & 1u);
  return (short)(r >> 16);
}

// asm global load: cannot be sunk/collapsed by the scheduler (r9/r10 showed
// hipcc serializes C++ loads regardless of unrolling / launch_bounds).
#define GLOAD16(dst, base, OFF) \
  asm volatile("global_load_dwordx4 %0, %1, off offset:" #OFF \
               : "=v"(dst) : "v"(base) : "memory")

#define LOAD8(ARR, BASE) do { \
  GLOAD16(ARR[0], (BASE), 0);   GLOAD16(ARR[1], (BASE), 64);  \
  GLOAD16(ARR[2], (BASE), 128); GLOAD16(ARR[3], (BASE), 192); \
  GLOAD16(ARR[4], (BASE), 256); GLOAD16(ARR[5], (BASE), 320); \
  GLOAD16(ARR[6], (BASE), 384); GLOAD16(ARR[7], (BASE), 448); \
} while(0)

// counted waits; sched_barrier stops register-only MFMAs hoisting above the
// waitcnt (guide rule #18)
#define WAIT_VM8() do { asm volatile("s_waitcnt vmcnt(8)" ::: "memory"); \
                        __builtin_amdgcn_sched_barrier(0); } while(0)
#define WAIT_VM0() do { asm volatile("s_waitcnt vmcnt(0)" ::: "memory"); \
                        __builtin_amdgcn_sched_barrier(0); } while(0)

// Slot barrier for 256 blocks: block i stores phase to slots[i] (agent
// write-through); wave 0 polls 4 slots/lane. Callers must have made all
// cross-block visible stores with agent-scope atomic stores (drained by the
// s_waitcnt(0) here before signaling). Acquire = agent fence (invalidate).
__device__ __forceinline__ void treebarS(int* slots, int* phase){
  asm volatile("" ::: "memory");
  __builtin_amdgcn_s_waitcnt(0);
  asm volatile("" ::: "memory");
  __syncthreads();
  int ph = *phase + 1;
  if (threadIdx.x == 0)
    __hip_atomic_store(&slots[blockIdx.x], ph, __ATOMIC_RELAXED, __HIP_MEMORY_SCOPE_AGENT);
  if (threadIdx.x < 64){
    int base = threadIdx.x << 2;
    int spins = 0;
    for (;;){
      int a = __hip_atomic_load(&slots[base+0], __ATOMIC_RELAXED, __HIP_MEMORY_SCOPE_AGENT);
      int b = __hip_atomic_load(&slots[base+1], __ATOMIC_RELAXED, __HIP_MEMORY_SCOPE_AGENT);
      int c = __hip_atomic_load(&slots[base+2], __ATOMIC_RELAXED, __HIP_MEMORY_SCOPE_AGENT);
      int d = __hip_atomic_load(&slots[base+3], __ATOMIC_RELAXED, __HIP_MEMORY_SCOPE_AGENT);
      int mn = min(min(a,b), min(c,d));
      if (__all(mn >= ph)) break;
      if (++spins > 128) __builtin_amdgcn_s_sleep(1);
    }
    __builtin_amdgcn_fence(__ATOMIC_ACQUIRE, "agent");
  }
  __syncthreads();
  (*phase)++;
}

// ---------------- k_rank: 4 emb rows per block, LDS-staged coalesced w1.
// Block 256 is the zero-duty block (merged former k_zero).
__global__ __launch_bounds__(128) void k_rank(const float* __restrict__ emb,
                                              const float* __restrict__ w1,
                                              const float* __restrict__ w2,
                                              float* __restrict__ SC,
                                              short* __restrict__ HG,
                                              int* __restrict__ LEVCNT,
                                              int* __restrict__ MAXLEV,
                                              int* __restrict__ NODECNT,
                                              int* __restrict__ BAR1,
                                              int* __restrict__ GRP){
  if (blockIdx.x == 256){
    int tid = threadIdx.x;
    for (int i = tid; i < 32768; i += 128) HG[i] = 0;
    if (tid < 64) LEVCNT[tid] = 0;
    if (tid == 64) MAXLEV[0] = 0;
    if (tid == 65) NODECNT[0] = 0;
    if (tid >= 66 && tid < 98) BAR1[tid - 66] = 0;
    GRP[tid] = 0; GRP[tid + 128] = 0;
    return;
  }
  __shared__ float WT[128][65];
  __shared__ float ES[4][64];
  __shared__ float red[4][128];
  int tid = threadIdx.x;
  int bl0 = blockIdx.x * 4;
  float acc0 = 0.f, acc1 = 0.f, acc2 = 0.f, acc3 = 0.f;
  for (int k0 = 0; k0 < 1024; k0 += 64){
    __syncthreads();
    #pragma unroll
    for (int it = 0; it < 16; it++){
      int idx = it*128 + tid;
      int rw = idx >> 4, c4 = (idx & 15) * 4;
      float4 v = *(const float4*)(w1 + rw*1024 + k0 + c4);
      WT[rw][c4+0] = v.x; WT[rw][c4+1] = v.y; WT[rw][c4+2] = v.z; WT[rw][c4+3] = v.w;
    }
    if (tid < 64){
      int r = tid >> 4, c4 = (tid & 15) * 4;
      float4 v = *(const float4*)(emb + (bl0 + r)*1024 + k0 + c4);
      ES[r][c4+0] = v.x; ES[r][c4+1] = v.y; ES[r][c4+2] = v.z; ES[r][c4+3] = v.w;
    }
    __syncthreads();
    #pragma unroll
    for (int c = 0; c < 64; c++){
      float wv = WT[tid][c];
      acc0 += wv * ES[0][c];
      acc1 += wv * ES[1][c];
      acc2 += wv * ES[2][c];
      acc3 += wv * ES[3][c];
    }
  }
  float w2v = w2[tid];
  red[0][tid] = fmaxf(acc0, 0.f) * w2v;
  red[1][tid] = fmaxf(acc1, 0.f) * w2v;
  red[2][tid] = fmaxf(acc2, 0.f) * w2v;
  red[3][tid] = fmaxf(acc3, 0.f) * w2v;
  __syncthreads();
  for (int st = 64; st > 0; st >>= 1){
    if (tid < st){
      red[0][tid] += red[0][tid + st];
      red[1][tid] += red[1][tid + st];
      red[2][tid] += red[2][tid + st];
      red[3][tid] += red[3][tid + st];
    }
    __syncthreads();
  }
  if (tid < 4) SC[bl0 + tid] = red[tid][0];
}

// ---------------- k_gx (MFMA bf16): GX[bl][r] = emb[bl]·w_ih[r] + b_ih[r] + b_hh[r]
__global__ __launch_bounds__(256) void k_gx(const float* __restrict__ emb,
                                            const float* __restrict__ w_ih,
                                            const float* __restrict__ b_ih,
                                            const float* __restrict__ b_hh,
                                            float* __restrict__ GX){
  __shared__ short Ws[64][72];
  __shared__ short Es[64][72];
  int mt = blockIdx.x >> 4;
  int nt4 = blockIdx.x & 15;
  int r0 = mt*64, n0 = nt4*64;
  int lane = threadIdx.x & 63, w = threadIdx.x >> 6;
  int m16 = lane & 15, quad = lane >> 4;
  int srr = threadIdx.x >> 2, skk = (threadIdx.x & 3)*16;
  f32x4 acc[4] = {{0,0,0,0},{0,0,0,0},{0,0,0,0},{0,0,0,0}};
  for (int k0 = 0; k0 < 1024; k0 += 64){
    #pragma unroll
    for (int i = 0; i < 4; i++){
      float4 v = *(const float4*)(w_ih + (r0 + srr)*1024 + k0 + skk + i*4);
      s16x4 wv; wv[0] = f2bf(v.x); wv[1] = f2bf(v.y); wv[2] = f2bf(v.z); wv[3] = f2bf(v.w);
      *(s16x4*)&Ws[srr][skk + i*4] = wv;
      float4 u = *(const float4*)(emb + (n0 + srr)*1024 + k0 + skk + i*4);
      s16x4 ev; ev[0] = f2bf(u.x); ev[1] = f2bf(u.y); ev[2] = f2bf(u.z); ev[3] = f2bf(u.w);
      *(s16x4*)&Es[srr][skk + i*4] = ev;
    }
    __syncthreads();
    #pragma unroll
    for (int ks = 0; ks < 64; ks += 32){
      bf16x8 a = *(bf16x8*)&Ws[w*16 + m16][ks + quad*8];
      #pragma unroll
      for (int nt = 0; nt < 4; nt++){
        bf16x8 b = *(bf16x8*)&Es[nt*16 + m16][ks + quad*8];
        acc[nt] = __builtin_amdgcn_mfma_f32_16x16x32_bf16(a, b, acc[nt], 0, 0, 0);
      }
    }
    __syncthreads();
  }
  int rbase = r0 + w*16 + quad*4;
  f32x4 bi = *(const f32x4*)(b_ih + rbase);
  f32x4 bh = *(const f32x4*)(b_hh + rbase);
  #pragma unroll
  for (int nt = 0; nt < 4; nt++){
    int n = n0 + nt*16 + m16;
    f32x4 o = acc[nt] + bi + bh;
    *(f32x4*)(GX + n*4096 + rbase) = o;
  }
}

// ---------------- k_build: wave-parallel tree build, batched atomics
__global__ __launch_bounds__(64) void k_build(const float* __restrict__ SC,
      const int* __restrict__ length,
      int* __restrict__ LCH, int* __restrict__ RCH, int* __restrict__ ISNODE,
      int* __restrict__ LEVCNT, int* __restrict__ LEVLIST, int* __restrict__ LEVEID,
      int* __restrict__ EINFO, int* __restrict__ PARENTREF, int* __restrict__ NODECNT,
      int* __restrict__ ROOTP, int* __restrict__ MAXLEV, float* __restrict__ OUT){
  __shared__ int stk_s[64], stk_e[64], stk_p[64];
  __shared__ int order_l[64], ns_l[64], ne_l[64];
  __shared__ int lch_l[64], rch_l[64], isn_l[64], lev_l[64];
  __shared__ int par_l[64], seg_l[64], eid_l[64];
  __shared__ int hist[64], hbase[64], hrk[64];
  int b = blockIdx.x;
  int q = threadIdx.x;
  float sc_q = SC[b*64 + q];
  isn_l[q] = 0; hist[q] = 0; hrk[q] = 0; lch_l[q] = -1; rch_l[q] = -1;
  __syncthreads();
  int len = length[b];
  int cnt = 0, sp = 0;
  if (len >= 2){ stk_s[0] = 0; stk_e[0] = len; stk_p[0] = -1; sp = 1; }
  // All 64 lanes execute this loop with uniform control flow; stack writes are
  // uniform-value same-address (each lane sees its own write).
  while (sp > 0){
    sp--;
    int s = stk_s[sp], e = stk_e[sp], pp = stk_p[sp];
    float val = (q >= s && q < e) ? sc_q : -1e30f;
    int idx = q;
    #pragma unroll
    for (int st = 32; st > 0; st >>= 1){
      float ov = __shfl_xor(val, st, 64);
      int   oi = __shfl_xor(idx, st, 64);
      if (ov > val || (ov == val && oi < idx)){ val = ov; idx = oi; }  // first-max tie-break
    }
    int pos = idx;  // uniform
    order_l[cnt] = pos; ns_l[pos] = s; ne_l[pos] = e; isn_l[pos] = 1;
    if (pp >= 0){
      int ppos = pp >> 1, side = pp & 1;
      if (side) rch_l[ppos] = pos; else lch_l[ppos] = pos;
      par_l[pos] = ppos; seg_l[pos] = side;
    } else par_l[pos] = -1;
    int ll = pos - s, rl = e - pos - 1;
    if (ll == 1) lch_l[pos] = s;
    else if (ll >= 2){ stk_s[sp] = s; stk_e[sp] = pos; stk_p[sp] = pos << 1; sp++; }
    if (rl == 1) rch_l[pos] = pos + 1;
    else if (rl >= 2){ stk_s[sp] = pos + 1; stk_e[sp] = e; stk_p[sp] = (pos << 1) | 1; sp++; }
    cnt++;
  }
  // level assignment (children appear after parent in order => reverse pass)
  for (int i = cnt - 1; i >= 0; i--){
    int p = order_l[i];
    int lv = 0;
    int lq = lch_l[p];
    if (lq >= 0 && isn_l[lq]) lv = lev_l[lq] + 1;
    int rq = rch_l[p];
    if (rq >= 0 && isn_l[rq] && lev_l[rq] + 1 > lv) lv = lev_l[rq] + 1;
    lev_l[p] = lv;
  }
  __syncthreads();
  if (q < cnt) atomicAdd(&hist[lev_l[order_l[q]]], 1);
  __syncthreads();
  int ebase0 = 0;
  if (q == 0 && cnt > 0) ebase0 = atomicAdd(NODECNT, cnt);
  ebase0 = __shfl(ebase0, 0, 64);
  if (hist[q] > 0) hbase[q] = atomicAdd(&LEVCNT[q], hist[q]);  // one parallel round
  __syncthreads();
  if (q < cnt){
    int p = order_l[q];
    int lv = lev_l[p];
    int slot = hbase[lv] + atomicAdd(&hrk[lv], 1);
    int eid = ebase0 + q;
    eid_l[p] = eid;
    LEVLIST[lv*512 + slot] = (b << 8) | p;
    LEVEID[lv*512 + slot]  = eid;
    EINFO[eid] = (b << 8) | p;
  }
  __syncthreads();
  if (q < cnt){
    int p = order_l[q];
    PARENTREF[ebase0 + q] = (par_l[p] >= 0) ? (eid_l[par_l[p]]*2 + seg_l[p]) : -1;
  }
  LCH[b*64 + q] = lch_l[q];
  RCH[b*64 + q] = rch_l[q];
  ISNODE[b*64 + q] = isn_l[q];
  if (q == 0){
    ROOTP[b] = (cnt > 0) ? order_l[0] : 0;
    if (cnt > 0) atomicMax(MAXLEV, lev_l[order_l[0]]);
  }
  // REINFORCE log-prob terms, wave-parallel per node
  float lp = 0.f;
  for (int i = 0; i < cnt; i++){
    int p = order_l[i], s = ns_l[p], e = ne_l[p];
    bool in = (q >= s && q < e);
    float v = in ? sc_q : -1e30f;
    #pragma unroll
    for (int st = 32; st > 0; st >>= 1) v = fmaxf(v, __shfl_xor(v, st, 64));
    float ex = in ? expf(sc_q - v) : 0.f;
    #pragma unroll
    for (int st = 32; st > 0; st >>= 1) ex += __shfl_xor(ex, st, 64);
    float scp = __shfl(sc_q, p, 64);
    lp += (float)(e - s) * (scp - (v + logf(ex)));
  }
  if (q == 0) OUT[32768 + b] = lp;
}

// ---------------- k_lstm (cooperative, 32 blocks x 512) — round-7 known-good.
__global__ __launch_bounds__(512, 2) void k_lstm(const float* __restrict__ w_hh,
      const float* __restrict__ GX, float* __restrict__ HS, float* __restrict__ CS,
      short* __restrict__ HG, int* __restrict__ SLOTS){
  __shared__ float EX[4][32][17];
  __shared__ short HGs[16384];     // 32 KB staged h (bf16, [ch>>3][batch][ch&7])
  int bi = blockIdx.x;
  int w = threadIdx.x >> 6, lane = threadIdx.x & 63;
  int quad = lane >> 4, m16 = lane & 15;
  int gate = w >> 1, jhalf = w & 1;
  int j0 = bi*32;
  int row = gate*1024 + j0 + jhalf*16 + m16;
  bf16x8 Wf[32];
  #pragma unroll
  for (int ks = 0; ks < 32; ks++){
    const float* p = w_hh + row*1024 + ks*32 + quad*8;
    float4 a = *(const float4*)p;
    float4 b = *(const float4*)(p + 4);
    bf16x8 o;
    o[0]=f2bf(a.x); o[1]=f2bf(a.y); o[2]=f2bf(a.z); o[3]=f2bf(a.w);
    o[4]=f2bf(b.x); o[5]=f2bf(b.y); o[6]=f2bf(b.z); o[7]=f2bf(b.w);
    Wf[ks] = o;
  }
  int tid = threadIdx.x;
  int ojl = tid & 31;        // channel-in-block (coalescing remap)
  int ob  = tid >> 5;        // batch
  int oj = j0 + ojl;
  float creg = 0.f;
  int jloc_base = jhalf*16 + quad*4;
  int phase = 0;
  const float* gxp = GX + ob*64*4096 + oj;
  float4 pg, pg2;
  pg.x = gxp[0]; pg.y = gxp[1024]; pg.z = gxp[2048]; pg.w = gxp[3072];
  for (int t = 0; t < 64; t++){
    const short* HR = HG + (t & 1)*16384;
    short* HW = HG + ((t + 1) & 1)*16384;
    f32x4 acc = {0.f,0.f,0.f,0.f};
    f32x4 a1 = {0.f,0.f,0.f,0.f}, a2 = {0.f,0.f,0.f,0.f}, a3 = {0.f,0.f,0.f,0.f};
    if (t > 0){
      // issue all 4 granule loads (consecutive lanes -> consecutive 16B)
      float4 s0 = *(const float4*)(HR + (0*512 + tid)*8);
      float4 s1 = *(const float4*)(HR + (1*512 + tid)*8);
      float4 s2 = *(const float4*)(HR + (2*512 + tid)*8);
      float4 s3 = *(const float4*)(HR + (3*512 + tid)*8);
      if (t < 63){   // next-step gx prefetch rides with stage loads
        const float* g2 = gxp + (t + 1)*4096;
        pg2.x = g2[0]; pg2.y = g2[1024]; pg2.z = g2[2048]; pg2.w = g2[3072];
      }
      // half 1 (channels 0..511 -> HGs bytes < 16KB)
      *(float4*)&HGs[(0*512 + tid)*8] = s0;
      *(float4*)&HGs[(1*512 + tid)*8] = s1;
      __syncthreads();
      #pragma unroll
      for (int ks = 0; ks < 16; ks += 4){
        bf16x8 b0 = *(const bf16x8*)&HGs[(ks*4     + quad)*128 + m16*8];
        bf16x8 b1 = *(const bf16x8*)&HGs[((ks+1)*4 + quad)*128 + m16*8];
        bf16x8 b2 = *(const bf16x8*)&HGs[((ks+2)*4 + quad)*128 + m16*8];
        bf16x8 b3 = *(const bf16x8*)&HGs[((ks+3)*4 + quad)*128 + m16*8];
        acc = __builtin_amdgcn_mfma_f32_16x16x32_bf16(Wf[ks],   b0, acc, 0, 0, 0);
        a1  = __builtin_amdgcn_mfma_f32_16x16x32_bf16(Wf[ks+1], b1, a1,  0, 0, 0);
        a2  = __builtin_amdgcn_mfma_f32_16x16x32_bf16(Wf[ks+2], b2, a2,  0, 0, 0);
        a3  = __builtin_amdgcn_mfma_f32_16x16x32_bf16(Wf[ks+3], b3, a3,  0, 0, 0);
      }
      // half 2 (channels 512..1023 -> HGs bytes >= 16KB; loads landed under MFMA)
      *(float4*)&HGs[(2*512 + tid)*8] = s2;
      *(float4*)&HGs[(3*512 + tid)*8] = s3;
      __syncthreads();
      #pragma unroll
      for (int ks = 16; ks < 32; ks += 4){
        bf16x8 b0 = *(const bf16x8*)&HGs[(ks*4     + quad)*128 + m16*8];
        bf16x8 b1 = *(const bf16x8*)&HGs[((ks+1)*4 + quad)*128 + m16*8];
        bf16x8 b2 = *(const bf16x8*)&HGs[((ks+2)*4 + quad)*128 + m16*8];
        bf16x8 b3 = *(const bf16x8*)&HGs[((ks+3)*4 + quad)*128 + m16*8];
        acc = __builtin_amdgcn_mfma_f32_16x16x32_bf16(Wf[ks],   b0, acc, 0, 0, 0);
        a1  = __builtin_amdgcn_mfma_f32_16x16x32_bf16(Wf[ks+1], b1, a1,  0, 0, 0);
        a2  = __builtin_amdgcn_mfma_f32_16x16x32_bf16(Wf[ks+2], b2, a2,  0, 0, 0);
        a3  = __builtin_amdgcn_mfma_f32_16x16x32_bf16(Wf[ks+3], b3, a3,  0, 0, 0);
      }
      acc = (acc + a1) + (a2 + a3);
      // (no barrier needed here: next HGs write is >=2 barriers away)
    } else {
      if (t < 63){
        const float* g2 = gxp + (t + 1)*4096;
        pg2.x = g2[0]; pg2.y = g2[1024]; pg2.z = g2[2048]; pg2.w = g2[3072];
      }
    }
    #pragma unroll
    for (int r = 0; r < 4; r++) EX[gate][jloc_base + r][m16] = acc[r];
    __syncthreads();
    float gi = EX[0][ojl][ob] + pg.x;
    float gf = EX[1][ojl][ob] + pg.y;
    float gu = EX[2][ojl][ob] + pg.z;
    float go = EX[3][ojl][ob] + pg.w;
    float cc = fsig(gf)*creg + fsig(gi)*ftanh(gu);
    float hh = fsig(go)*ftanh(cc);
    creg = cc;
    __hip_atomic_store(&HW[(oj >> 3)*128 + ob*8 + (oj & 7)], f2bf(hh),
                       __ATOMIC_RELAXED, __HIP_MEMORY_SCOPE_AGENT);
    if (t < 63){
      pg = pg2;
      asm volatile("" ::: "memory");
      __builtin_amdgcn_s_waitcnt(0);   // drains HW store (stage/prefetch already done)
      asm volatile("" ::: "memory");
      __syncthreads();
      // result stores issued here stay in flight during the spin (coalesced)
      HS[(ob*64 + t)*1024 + oj] = hh;
      CS[(ob*64 + t)*1024 + oj] = cc;
      int ph = phase + 1;
      if (tid == 0)
        __hip_atomic_store(&SLOTS[bi], ph, __ATOMIC_RELAXED, __HIP_MEMORY_SCOPE_AGENT);
      if (tid < 64){
        int spins = 0;
        for (;;){
          int v = __hip_atomic_load(&SLOTS[lane & 31], __ATOMIC_RELAXED, __HIP_MEMORY_SCOPE_AGENT);
          if (__all(v >= ph)) break;
          if (++spins > 128) __builtin_amdgcn_s_sleep(1);
        }
        __builtin_amdgcn_fence(__ATOMIC_ACQUIRE, "agent");
      }
      __syncthreads();
      phase = ph;
    } else {
      HS[(ob*64 + t)*1024 + oj] = hh;
      CS[(ob*64 + t)*1024 + oj] = cc;
    }
  }
}

// ---------------- k_tree3 (cooperative, 256 blocks x 512 — 8 waves)
// K-loop now uses inline-asm global_load_dwordx4 + counted s_waitcnt vmcnt(8)
// in a 2-chunk double buffer (AITER pattern): the compiler provably sinks C++
// loads to their uses regardless of unrolling/launch_bounds (r9: VGPR=52,
// r10: VGPR=40, both flat), so explicit asm is the only way to keep 8 loads
// in flight across the MFMA chunk. No other VMEM ops exist inside the counted
// region (A-operands are LDS/lgkm; scalar loads pinned before by the asm
// "memory" clobbers; stores depend on results). sched_barrier(0) after each
// waitcnt per rule #18.
__global__ __launch_bounds__(512, 2) void k_tree3(const float* __restrict__ tl_w,
      const float* __restrict__ tl_b,
      float* __restrict__ HS, float* __restrict__ CS,
      const int* __restrict__ LCH, const int* __restrict__ RCH,
      const int* __restrict__ ISNODE,
      const int* __restrict__ LEVCNT, const int* __restrict__ LEVLIST,
      const int* __restrict__ LEVEID, const int* __restrict__ EINFO,
      const int* __restrict__ PARENTREF, const int* __restrict__ NODECNT,
      const int* __restrict__ MAXLEV, short* __restrict__ HCAT,
      const int* __restrict__ ROOTP, float* __restrict__ OUT,
      int* __restrict__ SLOTS){
  extern __shared__ short WL[];                 // 24 rows x 3080 shorts
  float* EXF = (float*)(WL + 24*3080);          // 8 waves x 400 floats
  int bi = blockIdx.x;
  int J0 = bi*4;
  for (int gidx = threadIdx.x; gidx < 24*384; gidx += 512){
    int ri = gidx / 384;
    int col = (gidx % 384)*8;
    int g = ri >> 2, c = ri & 3;
    const float* p = tl_w + (g*1024 + J0 + c)*3072 + col;
    float4 a = *(const float4*)p;
    float4 b2 = *(const float4*)(p + 4);
    bf16x8 o;
    o[0]=f2bf(a.x); o[1]=f2bf(a.y); o[2]=f2bf(a.z); o[3]=f2bf(a.w);
    o[4]=f2bf(b2.x); o[5]=f2bf(b2.y); o[6]=f2bf(b2.z); o[7]=f2bf(b2.w);
    *(bf16x8*)&WL[ri*3080 + col] = o;
  }
  int lane = threadIdx.x & 63, w = threadIdx.x >> 6;
  int m16 = lane & 15, quad = lane >> 4;
  int uj = J0 + quad;                 // this lane's update channel
  float tb[6];
  #pragma unroll
  for (int g = 0; g < 6; g++) tb[g] = tl_b[g*1024 + uj];
  __syncthreads();
  int phase = 0;
  // prefill HCAT (m-seg = leaf h; leaf/absent child segs)
  int ncnt = NODECNT[0];
  {
    int total = ncnt * 1024;
    for (int idx = bi*512 + threadIdx.x; idx < total; idx += 131072){
      int eid = idx >> 10, j = idx & 1023;
      int e = EINFO[eid]; int b = e >> 8, p = e & 255;
      __hip_atomic_store(&HCAT[eid*3072 + 2048 + j], f2bf(HS[(b*64 + p)*1024 + j]),
                         __ATOMIC_RELAXED, __HIP_MEMORY_SCOPE_AGENT);
      int lq = LCH[b*64 + p];
      if (lq < 0)
        __hip_atomic_store(&HCAT[eid*3072 + j], (short)0, __ATOMIC_RELAXED, __HIP_MEMORY_SCOPE_AGENT);
      else if (!ISNODE[b*64 + lq])
        __hip_atomic_store(&HCAT[eid*3072 + j], f2bf(HS[(b*64 + lq)*1024 + j]),
                           __ATOMIC_RELAXED, __HIP_MEMORY_SCOPE_AGENT);
      int rq = RCH[b*64 + p];
      if (rq < 0)
        __hip_atomic_store(&HCAT[eid*3072 + 1024 + j], (short)0, __ATOMIC_RELAXED, __HIP_MEMORY_SCOPE_AGENT);
      else if (!ISNODE[b*64 + rq])
        __hip_atomic_store(&HCAT[eid*3072 + 1024 + j], f2bf(HS[(b*64 + rq)*1024 + j]),
                           __ATOMIC_RELAXED, __HIP_MEMORY_SCOPE_AGENT);
    }
  }
  treebarS(SLOTS, &phase);
  int maxlev = MAXLEV[0];
  for (int v = 0; v <= maxlev; v++){
    int nc = LEVCNT[v];
    int ntiles = (nc + 15) >> 4;
    for (int nt = w; nt < ntiles; nt += 8){
      int n = nt*16 + m16;
      bool valid = (n < nc);
      int eid = valid ? LEVEID[v*512 + n] : 1023;
      int e   = valid ? LEVLIST[v*512 + n] : 0;
      int b = e >> 8, p = e & 255;
      int lq = valid ? LCH[b*64 + p] : -1;
      int rq = valid ? RCH[b*64 + p] : -1;
      int pr = valid ? PARENTREF[eid] : -1;
      float cl = (valid && lq >= 0) ? CS[(b*64 + lq)*1024 + uj] : 0.f;
      float cr = (valid && rq >= 0) ? CS[(b*64 + rq)*1024 + uj] : 0.f;
      float cm = valid ? CS[(b*64 + p)*1024 + uj] : 0.f;
      const short* bp  = HCAT + eid*3072 + quad*8;
      const short* a0p = WL + m16*3080 + quad*8;
      const short* a1p = WL + (16 + (m16 & 7))*3080 + quad*8;
      f32x4 acc0 = {0,0,0,0}, acc1 = {0,0,0,0};
      // asm-pipelined K-loop: 12 chunks of 8 x 64B loads; chunk c+1 issued
      // before chunk c's MFMAs, vmcnt(8) guarantees chunk c landed while
      // c+1's 8 loads stay in flight.
      i32x4 A[8], B[8];
      #define COMPUTE8(ARR, KB) do { \
        _Pragma("unroll") \
        for (int i = 0; i < 8; i++){ \
          int k0 = (KB) + i*32; \
          bf16x8 ta0 = *(const bf16x8*)(a0p + k0); \
          bf16x8 ta1 = *(const bf16x8*)(a1p + k0); \
          bf16x8 tb_ = *(const bf16x8*)&ARR[i]; \
          acc0 = __builtin_amdgcn_mfma_f32_16x16x32_bf16(ta0, tb_, acc0, 0, 0, 0); \
          acc1 = __builtin_amdgcn_mfma_f32_16x16x32_bf16(ta1, tb_, acc1, 0, 0, 0); \
        } \
      } while(0)
      LOAD8(A, bp);
      #pragma unroll
      for (int kc2 = 0; kc2 < 6; kc2++){
        int c0 = kc2*2;
        LOAD8(B, bp + (c0 + 1)*256);
        WAIT_VM8();
        COMPUTE8(A, c0*256);
        if (c0 + 2 < 12){
          LOAD8(A, bp + (c0 + 2)*256);
          WAIT_VM8();
        } else {
          WAIT_VM0();
        }
        COMPUTE8(B, (c0 + 1)*256);
      }
      #undef COMPUTE8
      // in-wave gate exchange: D row quad*4+r of acc0 = ri (g*4+c) 0..15;
      // acc1 rows map to ri 16+((quad*4+r)&7) (quads 2,3 duplicate 0,1)
      float* ex = EXF + w*400;
      #pragma unroll
      for (int r = 0; r < 4; r++) ex[m16*25 + quad*4 + r] = acc0[r];
      if (quad < 2){
        #pragma unroll
        for (int r = 0; r < 4; r++) ex[m16*25 + 16 + quad*4 + r] = acc1[r];
      }
      // update: lane = (node m16, channel quad)
      if (valid){
        float gv[6];
        #pragma unroll
        for (int g = 0; g < 6; g++) gv[g] = ex[m16*25 + g*4 + quad] + tb[g];
        float c = fsig(gv[1])*cl + fsig(gv[2])*cr + fsig(gv[3])*cm + fsig(gv[0])*ftanh(gv[4]);
        float h = fsig(gv[5])*ftanh(c);
        __hip_atomic_store(&HS[(b*64 + p)*1024 + uj], h, __ATOMIC_RELAXED, __HIP_MEMORY_SCOPE_AGENT);
        __hip_atomic_store(&CS[(b*64 + p)*1024 + uj], c, __ATOMIC_RELAXED, __HIP_MEMORY_SCOPE_AGENT);
        if (pr >= 0)
          __hip_atomic_store(&HCAT[(pr >> 1)*3072 + (pr & 1)*1024 + uj], f2bf(h),
                             __ATOMIC_RELAXED, __HIP_MEMORY_SCOPE_AGENT);
      }
    }
    treebarS(SLOTS, &phase);
  }
  // fused root gather
  for (int idx = bi*512 + threadIdx.x; idx < 32768; idx += 131072){
    int half = idx >> 14;
    int b = (idx >> 10) & 15, j = idx & 1023;
    int rp = ROOTP[b];
    OUT[half*16384 + b*1024 + j] = half ? CS[(b*64 + rp)*1024 + j]
                                        : HS[(b*64 + rp)*1024 + j];
  }
}

extern "C" void kernel_launch(void* const* d_in, const int* in_sizes, int n_in,
                              void* d_out, int out_size, void* d_ws, size_t ws_size,
                              hipStream_t stream) {
  (void)in_sizes; (void)n_in; (void)out_size; (void)ws_size;
  const float* emb    = (const float*)d_in[0];
  const int*   length = (const int*)  d_in[2];
  const float* w_ih   = (const float*)d_in[3];
  const float* w_hh   = (const float*)d_in[4];
  const float* b_ih   = (const float*)d_in[5];
  const float* b_hh   = (const float*)d_in[6];
  const float* tl_w   = (const float*)d_in[7];
  const float* tl_b   = (const float*)d_in[8];
  const float* rk_w1  = (const float*)d_in[9];
  const float* rk_w2  = (const float*)d_in[10];
  float* OUT = (float*)d_out;

  float* ws_f = (float*)d_ws;
  float* GX   = ws_f;                        // 4,194,304 f
  float* HS   = ws_f + 4194304;              // 1,048,576 f
  float* CS   = ws_f + 5242880;              // 1,048,576 f
  short* HCAT = (short*)(ws_f + 6291456);    // 1024*3072 shorts
  float* SC   = ws_f + 7864320;              // 1,024 f
  short* HG   = (short*)(ws_f + 7865344);    // 32,768 shorts
  int*   IW   = (int*)(ws_f + 7881728);
  int* LCH      = IW;               // 1024
  int* RCH      = IW + 1024;        // 1024
  int* ISNODE   = IW + 2048;        // 1024
  int* LEVCNT   = IW + 3072;        // 64
  int* LEVLIST  = IW + 3136;        // 32768
  int* LEVEID   = IW + 35904;       // 32768
  int* EINFO    = IW + 68672;       // 1024
  int* PARENTREF= IW + 69696;       // 1024
  int* ROOTP    = IW + 70720;       // 16
  int* MAXLEV   = IW + 70736;
  int* NODECNT  = IW + 70737;
  int* BAR1     = IW + 70752;       // 32 slots (k_lstm barrier)
  int* GRP      = IW + 70784;       // 256 slots (k_tree3 barrier)

  k_rank<<<257, 128, 0, stream>>>(emb, rk_w1, rk_w2, SC, HG, LEVCNT, MAXLEV,
                                  NODECNT, BAR1, GRP);
  k_gx<<<1024, 256, 0, stream>>>(emb, w_ih, b_ih, b_hh, GX);
  k_build<<<16, 64, 0, stream>>>(SC, length, LCH, RCH, ISNODE, LEVCNT, LEVLIST,
                                 LEVEID, EINFO, PARENTREF, NODECNT, ROOTP, MAXLEV, OUT);

  {
    void* args[] = { (void*)&w_hh, (void*)&GX, (void*)&HS, (void*)&CS, (void*)&HG,
                     (void*)&BAR1 };
    hipLaunchCooperativeKernel((const void*)k_lstm, dim3(32), dim3(512), args, 0, stream);
  }
  {
    hipFuncSetAttribute((const void*)k_tree3,
                        hipFuncAttributeMaxDynamicSharedMemorySize, 160640);
    void* args[] = { (void*)&tl_w, (void*)&tl_b, (void*)&HS, (void*)&CS,
                     (void*)&LCH, (void*)&RCH, (void*)&ISNODE,
                     (void*)&LEVCNT, (void*)&LEVLIST, (void*)&LEVEID, (void*)&EINFO,
                     (void*)&PARENTREF, (void*)&NODECNT, (void*)&MAXLEV,
                     (void*)&HCAT, (void*)&ROOTP, (void*)&OUT,
                     (void*)&GRP };
    hipLaunchCooperativeKernel((const void*)k_tree3, dim3(256), dim3(512), args,
                               160640, stream);
  }
}

// Round 12
// 817.518 us; speedup vs baseline: 1.0683x; 1.0095x over previous
//
#include <hip/hip_runtime.h>

typedef __attribute__((ext_vector_type(8))) short bf16x8;
typedef __attribute__((ext_vector_type(4))) short s16x4;
typedef __attribute__((ext_vector_type(4))) float f32x4;
typedef __attribute__((ext_vector_type(4))) int i32x4;

__device__ __forceinline__ float fsig(float x){ return 1.0f/(1.0f + __expf(-x)); }
__device__ __forceinline__ float ftanh(float x){
  x = fminf(fmaxf(x, -15.f), 15.f);
  float e = __expf(2.f*x);
  return (e - 1.f)/(e + 1.f);
}

__device__ __forceinline__ short f2bf(float x){
  union { float f; unsigned u; } v; v.f = x;
  unsigned r = v.u + 0x7fffu + ((v.u >> 16) & 1u);
  return (short)(r >> 16);
}

// asm global load: cannot be sunk/collapsed by the scheduler (r9/r10 showed
// hipcc serializes C++ loads regardless of unrolling / launch_bounds).
#define GLOAD16(dst, base, OFF) \
  asm volatile("global_load_dwordx4 %0, %1, off offset:" #OFF \
               : "=v"(dst) : "v"(base) : "memory")

#define LOAD8(ARR, BASE) do { \
  GLOAD16(ARR[0], (BASE), 0);   GLOAD16(ARR[1], (BASE), 64);  \
  GLOAD16(ARR[2], (BASE), 128); GLOAD16(ARR[3], (BASE), 192); \
  GLOAD16(ARR[4], (BASE), 256); GLOAD16(ARR[5], (BASE), 320); \
  GLOAD16(ARR[6], (BASE), 384); GLOAD16(ARR[7], (BASE), 448); \
} while(0)

// counted waits; sched_barrier stops register-only MFMAs hoisting above the
// waitcnt (guide rule #18)
#define WAIT_VM8() do { asm volatile("s_waitcnt vmcnt(8)" ::: "memory"); \
                        __builtin_amdgcn_sched_barrier(0); } while(0)
#define WAIT_VM0() do { asm volatile("s_waitcnt vmcnt(0)" ::: "memory"); \
                        __builtin_amdgcn_sched_barrier(0); } while(0)

// Slot barrier for 256 blocks: block i stores phase to slots[i] (agent
// write-through); wave 0 polls 4 slots/lane with PING-PONG polling (one poll
// always in flight -> detection ~0.5 MALL RTT instead of ~1.5). Callers must
// have made all cross-block visible stores with agent-scope atomic stores
// (drained by the s_waitcnt(0) here before signaling). Acquire fence after.
__device__ __forceinline__ void treebarS(int* slots, int* phase){
  asm volatile("" ::: "memory");
  __builtin_amdgcn_s_waitcnt(0);
  asm volatile("" ::: "memory");
  __syncthreads();
  int ph = *phase + 1;
  if (threadIdx.x == 0)
    __hip_atomic_store(&slots[blockIdx.x], ph, __ATOMIC_RELAXED, __HIP_MEMORY_SCOPE_AGENT);
  if (threadIdx.x < 64){
    int base = threadIdx.x << 2;
    int spins = 0;
    int a0 = __hip_atomic_load(&slots[base+0], __ATOMIC_RELAXED, __HIP_MEMORY_SCOPE_AGENT);
    int b0 = __hip_atomic_load(&slots[base+1], __ATOMIC_RELAXED, __HIP_MEMORY_SCOPE_AGENT);
    int c0 = __hip_atomic_load(&slots[base+2], __ATOMIC_RELAXED, __HIP_MEMORY_SCOPE_AGENT);
    int d0 = __hip_atomic_load(&slots[base+3], __ATOMIC_RELAXED, __HIP_MEMORY_SCOPE_AGENT);
    for (;;){
      int a1 = __hip_atomic_load(&slots[base+0], __ATOMIC_RELAXED, __HIP_MEMORY_SCOPE_AGENT);
      int b1 = __hip_atomic_load(&slots[base+1], __ATOMIC_RELAXED, __HIP_MEMORY_SCOPE_AGENT);
      int c1 = __hip_atomic_load(&slots[base+2], __ATOMIC_RELAXED, __HIP_MEMORY_SCOPE_AGENT);
      int d1 = __hip_atomic_load(&slots[base+3], __ATOMIC_RELAXED, __HIP_MEMORY_SCOPE_AGENT);
      int mn = min(min(a0,b0), min(c0,d0));
      if (__all(mn >= ph)) break;
      a0 = a1; b0 = b1; c0 = c1; d0 = d1;
      if (++spins > 1024) __builtin_amdgcn_s_sleep(1);
    }
    __builtin_amdgcn_fence(__ATOMIC_ACQUIRE, "agent");
  }
  __syncthreads();
  (*phase)++;
}

// ---------------- k_prep: one-time bf16 conversion of w_ih and emb.
// Outputs live in the HS/CS(+HCAT head) workspace region, which is only
// written by k_lstm/k_tree3 AFTER k_gx has consumed these (stream order).
__global__ __launch_bounds__(256) void k_prep(const float* __restrict__ w_ih,
                                              const float* __restrict__ emb,
                                              short* __restrict__ WIB,
                                              short* __restrict__ EMBB){
  int idx = blockIdx.x*256 + threadIdx.x;   // chunk of 8 floats
  if (idx < 524288){                        // w_ih: 4,194,304 floats
    const float* s = w_ih + idx*8;
    float4 a = *(const float4*)s;
    float4 b = *(const float4*)(s + 4);
    bf16x8 o;
    o[0]=f2bf(a.x); o[1]=f2bf(a.y); o[2]=f2bf(a.z); o[3]=f2bf(a.w);
    o[4]=f2bf(b.x); o[5]=f2bf(b.y); o[6]=f2bf(b.z); o[7]=f2bf(b.w);
    *(bf16x8*)(WIB + idx*8) = o;
  } else if (idx < 655360){                 // emb: 1,048,576 floats
    int j = idx - 524288;
    const float* s = emb + j*8;
    float4 a = *(const float4*)s;
    float4 b = *(const float4*)(s + 4);
    bf16x8 o;
    o[0]=f2bf(a.x); o[1]=f2bf(a.y); o[2]=f2bf(a.z); o[3]=f2bf(a.w);
    o[4]=f2bf(b.x); o[5]=f2bf(b.y); o[6]=f2bf(b.z); o[7]=f2bf(b.w);
    *(bf16x8*)(EMBB + j*8) = o;
  }
}

// ---------------- k_rank: 4 emb rows per block, LDS-staged coalesced w1.
// Block 256 is the zero-duty block (merged former k_zero).
__global__ __launch_bounds__(128) void k_rank(const float* __restrict__ emb,
                                              const float* __restrict__ w1,
                                              const float* __restrict__ w2,
                                              float* __restrict__ SC,
                                              short* __restrict__ HG,
                                              int* __restrict__ LEVCNT,
                                              int* __restrict__ MAXLEV,
                                              int* __restrict__ NODECNT,
                                              int* __restrict__ BAR1,
                                              int* __restrict__ GRP){
  if (blockIdx.x == 256){
    int tid = threadIdx.x;
    for (int i = tid; i < 32768; i += 128) HG[i] = 0;
    if (tid < 64) LEVCNT[tid] = 0;
    if (tid == 64) MAXLEV[0] = 0;
    if (tid == 65) NODECNT[0] = 0;
    if (tid >= 66 && tid < 98) BAR1[tid - 66] = 0;
    GRP[tid] = 0; GRP[tid + 128] = 0;
    return;
  }
  __shared__ float WT[128][65];
  __shared__ float ES[4][64];
  __shared__ float red[4][128];
  int tid = threadIdx.x;
  int bl0 = blockIdx.x * 4;
  float acc0 = 0.f, acc1 = 0.f, acc2 = 0.f, acc3 = 0.f;
  for (int k0 = 0; k0 < 1024; k0 += 64){
    __syncthreads();
    #pragma unroll
    for (int it = 0; it < 16; it++){
      int idx = it*128 + tid;
      int rw = idx >> 4, c4 = (idx & 15) * 4;
      float4 v = *(const float4*)(w1 + rw*1024 + k0 + c4);
      WT[rw][c4+0] = v.x; WT[rw][c4+1] = v.y; WT[rw][c4+2] = v.z; WT[rw][c4+3] = v.w;
    }
    if (tid < 64){
      int r = tid >> 4, c4 = (tid & 15) * 4;
      float4 v = *(const float4*)(emb + (bl0 + r)*1024 + k0 + c4);
      ES[r][c4+0] = v.x; ES[r][c4+1] = v.y; ES[r][c4+2] = v.z; ES[r][c4+3] = v.w;
    }
    __syncthreads();
    #pragma unroll
    for (int c = 0; c < 64; c++){
      float wv = WT[tid][c];
      acc0 += wv * ES[0][c];
      acc1 += wv * ES[1][c];
      acc2 += wv * ES[2][c];
      acc3 += wv * ES[3][c];
    }
  }
  float w2v = w2[tid];
  red[0][tid] = fmaxf(acc0, 0.f) * w2v;
  red[1][tid] = fmaxf(acc1, 0.f) * w2v;
  red[2][tid] = fmaxf(acc2, 0.f) * w2v;
  red[3][tid] = fmaxf(acc3, 0.f) * w2v;
  __syncthreads();
  for (int st = 64; st > 0; st >>= 1){
    if (tid < st){
      red[0][tid] += red[0][tid + st];
      red[1][tid] += red[1][tid + st];
      red[2][tid] += red[2][tid + st];
      red[3][tid] += red[3][tid + st];
    }
    __syncthreads();
  }
  if (tid < 4) SC[bl0 + tid] = red[tid][0];
}

// ---------------- k_gx (MFMA bf16): GX[bl][r] = emb[bl]·w_ih[r] + b_ih[r] + b_hh[r]
// Stages pre-converted bf16 (k_prep): half the global bytes, zero f2bf VALU.
__global__ __launch_bounds__(256) void k_gx(const short* __restrict__ WIB,
                                            const short* __restrict__ EMBB,
                                            const float* __restrict__ b_ih,
                                            const float* __restrict__ b_hh,
                                            float* __restrict__ GX){
  __shared__ short Ws[64][72];
  __shared__ short Es[64][72];
  int mt = blockIdx.x >> 4;
  int nt4 = blockIdx.x & 15;
  int r0 = mt*64, n0 = nt4*64;
  int lane = threadIdx.x & 63, w = threadIdx.x >> 6;
  int m16 = lane & 15, quad = lane >> 4;
  int srr = threadIdx.x >> 2, skk = (threadIdx.x & 3)*16;
  f32x4 acc[4] = {{0,0,0,0},{0,0,0,0},{0,0,0,0},{0,0,0,0}};
  for (int k0 = 0; k0 < 1024; k0 += 64){
    {
      const short* wp = WIB + (r0 + srr)*1024 + k0 + skk;
      bf16x8 w0 = *(const bf16x8*)wp;
      bf16x8 w1 = *(const bf16x8*)(wp + 8);
      const short* ep = EMBB + (n0 + srr)*1024 + k0 + skk;
      bf16x8 e0 = *(const bf16x8*)ep;
      bf16x8 e1 = *(const bf16x8*)(ep + 8);
      *(bf16x8*)&Ws[srr][skk]     = w0;
      *(bf16x8*)&Ws[srr][skk + 8] = w1;
      *(bf16x8*)&Es[srr][skk]     = e0;
      *(bf16x8*)&Es[srr][skk + 8] = e1;
    }
    __syncthreads();
    #pragma unroll
    for (int ks = 0; ks < 64; ks += 32){
      bf16x8 a = *(bf16x8*)&Ws[w*16 + m16][ks + quad*8];
      #pragma unroll
      for (int nt = 0; nt < 4; nt++){
        bf16x8 b = *(bf16x8*)&Es[nt*16 + m16][ks + quad*8];
        acc[nt] = __builtin_amdgcn_mfma_f32_16x16x32_bf16(a, b, acc[nt], 0, 0, 0);
      }
    }
    __syncthreads();
  }
  int rbase = r0 + w*16 + quad*4;
  f32x4 bi = *(const f32x4*)(b_ih + rbase);
  f32x4 bh = *(const f32x4*)(b_hh + rbase);
  #pragma unroll
  for (int nt = 0; nt < 4; nt++){
    int n = n0 + nt*16 + m16;
    f32x4 o = acc[nt] + bi + bh;
    *(f32x4*)(GX + n*4096 + rbase) = o;
  }
}

// ---------------- k_build: wave-parallel tree build, batched atomics
__global__ __launch_bounds__(64) void k_build(const float* __restrict__ SC,
      const int* __restrict__ length,
      int* __restrict__ LCH, int* __restrict__ RCH, int* __restrict__ ISNODE,
      int* __restrict__ LEVCNT, int* __restrict__ LEVLIST, int* __restrict__ LEVEID,
      int* __restrict__ EINFO, int* __restrict__ PARENTREF, int* __restrict__ NODECNT,
      int* __restrict__ ROOTP, int* __restrict__ MAXLEV, float* __restrict__ OUT){
  __shared__ int stk_s[64], stk_e[64], stk_p[64];
  __shared__ int order_l[64], ns_l[64], ne_l[64];
  __shared__ int lch_l[64], rch_l[64], isn_l[64], lev_l[64];
  __shared__ int par_l[64], seg_l[64], eid_l[64];
  __shared__ int hist[64], hbase[64], hrk[64];
  int b = blockIdx.x;
  int q = threadIdx.x;
  float sc_q = SC[b*64 + q];
  isn_l[q] = 0; hist[q] = 0; hrk[q] = 0; lch_l[q] = -1; rch_l[q] = -1;
  __syncthreads();
  int len = length[b];
  int cnt = 0, sp = 0;
  if (len >= 2){ stk_s[0] = 0; stk_e[0] = len; stk_p[0] = -1; sp = 1; }
  // All 64 lanes execute this loop with uniform control flow; stack writes are
  // uniform-value same-address (each lane sees its own write).
  while (sp > 0){
    sp--;
    int s = stk_s[sp], e = stk_e[sp], pp = stk_p[sp];
    float val = (q >= s && q < e) ? sc_q : -1e30f;
    int idx = q;
    #pragma unroll
    for (int st = 32; st > 0; st >>= 1){
      float ov = __shfl_xor(val, st, 64);
      int   oi = __shfl_xor(idx, st, 64);
      if (ov > val || (ov == val && oi < idx)){ val = ov; idx = oi; }  // first-max tie-break
    }
    int pos = idx;  // uniform
    order_l[cnt] = pos; ns_l[pos] = s; ne_l[pos] = e; isn_l[pos] = 1;
    if (pp >= 0){
      int ppos = pp >> 1, side = pp & 1;
      if (side) rch_l[ppos] = pos; else lch_l[ppos] = pos;
      par_l[pos] = ppos; seg_l[pos] = side;
    } else par_l[pos] = -1;
    int ll = pos - s, rl = e - pos - 1;
    if (ll == 1) lch_l[pos] = s;
    else if (ll >= 2){ stk_s[sp] = s; stk_e[sp] = pos; stk_p[sp] = pos << 1; sp++; }
    if (rl == 1) rch_l[pos] = pos + 1;
    else if (rl >= 2){ stk_s[sp] = pos + 1; stk_e[sp] = e; stk_p[sp] = (pos << 1) | 1; sp++; }
    cnt++;
  }
  // level assignment (children appear after parent in order => reverse pass)
  for (int i = cnt - 1; i >= 0; i--){
    int p = order_l[i];
    int lv = 0;
    int lq = lch_l[p];
    if (lq >= 0 && isn_l[lq]) lv = lev_l[lq] + 1;
    int rq = rch_l[p];
    if (rq >= 0 && isn_l[rq] && lev_l[rq] + 1 > lv) lv = lev_l[rq] + 1;
    lev_l[p] = lv;
  }
  __syncthreads();
  if (q < cnt) atomicAdd(&hist[lev_l[order_l[q]]], 1);
  __syncthreads();
  int ebase0 = 0;
  if (q == 0 && cnt > 0) ebase0 = atomicAdd(NODECNT, cnt);
  ebase0 = __shfl(ebase0, 0, 64);
  if (hist[q] > 0) hbase[q] = atomicAdd(&LEVCNT[q], hist[q]);  // one parallel round
  __syncthreads();
  if (q < cnt){
    int p = order_l[q];
    int lv = lev_l[p];
    int slot = hbase[lv] + atomicAdd(&hrk[lv], 1);
    int eid = ebase0 + q;
    eid_l[p] = eid;
    LEVLIST[lv*512 + slot] = (b << 8) | p;
    LEVEID[lv*512 + slot]  = eid;
    EINFO[eid] = (b << 8) | p;
  }
  __syncthreads();
  if (q < cnt){
    int p = order_l[q];
    PARENTREF[ebase0 + q] = (par_l[p] >= 0) ? (eid_l[par_l[p]]*2 + seg_l[p]) : -1;
  }
  LCH[b*64 + q] = lch_l[q];
  RCH[b*64 + q] = rch_l[q];
  ISNODE[b*64 + q] = isn_l[q];
  if (q == 0){
    ROOTP[b] = (cnt > 0) ? order_l[0] : 0;
    if (cnt > 0) atomicMax(MAXLEV, lev_l[order_l[0]]);
  }
  // REINFORCE log-prob terms, wave-parallel per node
  float lp = 0.f;
  for (int i = 0; i < cnt; i++){
    int p = order_l[i], s = ns_l[p], e = ne_l[p];
    bool in = (q >= s && q < e);
    float v = in ? sc_q : -1e30f;
    #pragma unroll
    for (int st = 32; st > 0; st >>= 1) v = fmaxf(v, __shfl_xor(v, st, 64));
    float ex = in ? expf(sc_q - v) : 0.f;
    #pragma unroll
    for (int st = 32; st > 0; st >>= 1) ex += __shfl_xor(ex, st, 64);
    float scp = __shfl(sc_q, p, 64);
    lp += (float)(e - s) * (scp - (v + logf(ex)));
  }
  if (q == 0) OUT[32768 + b] = lp;
}

// ---------------- k_lstm (cooperative, 32 blocks x 512) — round-7 structure
// + ping-pong flag polling (one poll always in flight, ~0.5 RTT detection).
__global__ __launch_bounds__(512, 2) void k_lstm(const float* __restrict__ w_hh,
      const float* __restrict__ GX, float* __restrict__ HS, float* __restrict__ CS,
      short* __restrict__ HG, int* __restrict__ SLOTS){
  __shared__ float EX[4][32][17];
  __shared__ short HGs[16384];     // 32 KB staged h (bf16, [ch>>3][batch][ch&7])
  int bi = blockIdx.x;
  int w = threadIdx.x >> 6, lane = threadIdx.x & 63;
  int quad = lane >> 4, m16 = lane & 15;
  int gate = w >> 1, jhalf = w & 1;
  int j0 = bi*32;
  int row = gate*1024 + j0 + jhalf*16 + m16;
  bf16x8 Wf[32];
  #pragma unroll
  for (int ks = 0; ks < 32; ks++){
    const float* p = w_hh + row*1024 + ks*32 + quad*8;
    float4 a = *(const float4*)p;
    float4 b = *(const float4*)(p + 4);
    bf16x8 o;
    o[0]=f2bf(a.x); o[1]=f2bf(a.y); o[2]=f2bf(a.z); o[3]=f2bf(a.w);
    o[4]=f2bf(b.x); o[5]=f2bf(b.y); o[6]=f2bf(b.z); o[7]=f2bf(b.w);
    Wf[ks] = o;
  }
  int tid = threadIdx.x;
  int ojl = tid & 31;        // channel-in-block (coalescing remap)
  int ob  = tid >> 5;        // batch
  int oj = j0 + ojl;
  float creg = 0.f;
  int jloc_base = jhalf*16 + quad*4;
  int phase = 0;
  const float* gxp = GX + ob*64*4096 + oj;
  float4 pg, pg2;
  pg.x = gxp[0]; pg.y = gxp[1024]; pg.z = gxp[2048]; pg.w = gxp[3072];
  for (int t = 0; t < 64; t++){
    const short* HR = HG + (t & 1)*16384;
    short* HW = HG + ((t + 1) & 1)*16384;
    f32x4 acc = {0.f,0.f,0.f,0.f};
    f32x4 a1 = {0.f,0.f,0.f,0.f}, a2 = {0.f,0.f,0.f,0.f}, a3 = {0.f,0.f,0.f,0.f};
    if (t > 0){
      // issue all 4 granule loads (consecutive lanes -> consecutive 16B)
      float4 s0 = *(const float4*)(HR + (0*512 + tid)*8);
      float4 s1 = *(const float4*)(HR + (1*512 + tid)*8);
      float4 s2 = *(const float4*)(HR + (2*512 + tid)*8);
      float4 s3 = *(const float4*)(HR + (3*512 + tid)*8);
      if (t < 63){   // next-step gx prefetch rides with stage loads
        const float* g2 = gxp + (t + 1)*4096;
        pg2.x = g2[0]; pg2.y = g2[1024]; pg2.z = g2[2048]; pg2.w = g2[3072];
      }
      // half 1 (channels 0..511 -> HGs bytes < 16KB)
      *(float4*)&HGs[(0*512 + tid)*8] = s0;
      *(float4*)&HGs[(1*512 + tid)*8] = s1;
      __syncthreads();
      #pragma unroll
      for (int ks = 0; ks < 16; ks += 4){
        bf16x8 b0 = *(const bf16x8*)&HGs[(ks*4     + quad)*128 + m16*8];
        bf16x8 b1 = *(const bf16x8*)&HGs[((ks+1)*4 + quad)*128 + m16*8];
        bf16x8 b2 = *(const bf16x8*)&HGs[((ks+2)*4 + quad)*128 + m16*8];
        bf16x8 b3 = *(const bf16x8*)&HGs[((ks+3)*4 + quad)*128 + m16*8];
        acc = __builtin_amdgcn_mfma_f32_16x16x32_bf16(Wf[ks],   b0, acc, 0, 0, 0);
        a1  = __builtin_amdgcn_mfma_f32_16x16x32_bf16(Wf[ks+1], b1, a1,  0, 0, 0);
        a2  = __builtin_amdgcn_mfma_f32_16x16x32_bf16(Wf[ks+2], b2, a2,  0, 0, 0);
        a3  = __builtin_amdgcn_mfma_f32_16x16x32_bf16(Wf[ks+3], b3, a3,  0, 0, 0);
      }
      // half 2 (channels 512..1023 -> HGs bytes >= 16KB; loads landed under MFMA)
      *(float4*)&HGs[(2*512 + tid)*8] = s2;
      *(float4*)&HGs[(3*512 + tid)*8] = s3;
      __syncthreads();
      #pragma unroll
      for (int ks = 16; ks < 32; ks += 4){
        bf16x8 b0 = *(const bf16x8*)&HGs[(ks*4     + quad)*128 + m16*8];
        bf16x8 b1 = *(const bf16x8*)&HGs[((ks+1)*4 + quad)*128 + m16*8];
        bf16x8 b2 = *(const bf16x8*)&HGs[((ks+2)*4 + quad)*128 + m16*8];
        bf16x8 b3 = *(const bf16x8*)&HGs[((ks+3)*4 + quad)*128 + m16*8];
        acc = __builtin_amdgcn_mfma_f32_16x16x32_bf16(Wf[ks],   b0, acc, 0, 0, 0);
        a1  = __builtin_amdgcn_mfma_f32_16x16x32_bf16(Wf[ks+1], b1, a1,  0, 0, 0);
        a2  = __builtin_amdgcn_mfma_f32_16x16x32_bf16(Wf[ks+2], b2, a2,  0, 0, 0);
        a3  = __builtin_amdgcn_mfma_f32_16x16x32_bf16(Wf[ks+3], b3, a3,  0, 0, 0);
      }
      acc = (acc + a1) + (a2 + a3);
      // (no barrier needed here: next HGs write is >=2 barriers away)
    } else {
      if (t < 63){
        const float* g2 = gxp + (t + 1)*4096;
        pg2.x = g2[0]; pg2.y = g2[1024]; pg2.z = g2[2048]; pg2.w = g2[3072];
      }
    }
    #pragma unroll
    for (int r = 0; r < 4; r++) EX[gate][jloc_base + r][m16] = acc[r];
    __syncthreads();
    float gi = EX[0][ojl][ob] + pg.x;
    float gf = EX[1][ojl][ob] + pg.y;
    float gu = EX[2][ojl][ob] + pg.z;
    float go = EX[3][ojl][ob] + pg.w;
    float cc = fsig(gf)*creg + fsig(gi)*ftanh(gu);
    float hh = fsig(go)*ftanh(cc);
    creg = cc;
    __hip_atomic_store(&HW[(oj >> 3)*128 + ob*8 + (oj & 7)], f2bf(hh),
                       __ATOMIC_RELAXED, __HIP_MEMORY_SCOPE_AGENT);
    if (t < 63){
      pg = pg2;
      asm volatile("" ::: "memory");
      __builtin_amdgcn_s_waitcnt(0);   // drains HW store (stage/prefetch already done)
      asm volatile("" ::: "memory");
      __syncthreads();
      // result stores issued here stay in flight during the spin (coalesced)
      HS[(ob*64 + t)*1024 + oj] = hh;
      CS[(ob*64 + t)*1024 + oj] = cc;
      int ph = phase + 1;
      if (tid == 0)
        __hip_atomic_store(&SLOTS[bi], ph, __ATOMIC_RELAXED, __HIP_MEMORY_SCOPE_AGENT);
      if (tid < 64){
        int spins = 0;
        int v0 = __hip_atomic_load(&SLOTS[lane & 31], __ATOMIC_RELAXED, __HIP_MEMORY_SCOPE_AGENT);
        for (;;){
          int v1 = __hip_atomic_load(&SLOTS[lane & 31], __ATOMIC_RELAXED, __HIP_MEMORY_SCOPE_AGENT);
          if (__all(v0 >= ph)) break;
          v0 = v1;
          if (++spins > 1024) __builtin_amdgcn_s_sleep(1);
        }
        __builtin_amdgcn_fence(__ATOMIC_ACQUIRE, "agent");
      }
      __syncthreads();
      phase = ph;
    } else {
      HS[(ob*64 + t)*1024 + oj] = hh;
      CS[(ob*64 + t)*1024 + oj] = cc;
    }
  }
}

// ---------------- k_tree3 (cooperative, 256 blocks x 512 — 8 waves)
// K-loop uses inline-asm global_load_dwordx4 + counted s_waitcnt vmcnt(8)
// in a 2-chunk double buffer (verified r11: k_tree3 285->~227us).
__global__ __launch_bounds__(512, 2) void k_tree3(const float* __restrict__ tl_w,
      const float* __restrict__ tl_b,
      float* __restrict__ HS, float* __restrict__ CS,
      const int* __restrict__ LCH, const int* __restrict__ RCH,
      const int* __restrict__ ISNODE,
      const int* __restrict__ LEVCNT, const int* __restrict__ LEVLIST,
      const int* __restrict__ LEVEID, const int* __restrict__ EINFO,
      const int* __restrict__ PARENTREF, const int* __restrict__ NODECNT,
      const int* __restrict__ MAXLEV, short* __restrict__ HCAT,
      const int* __restrict__ ROOTP, float* __restrict__ OUT,
      int* __restrict__ SLOTS){
  extern __shared__ short WL[];                 // 24 rows x 3080 shorts
  float* EXF = (float*)(WL + 24*3080);          // 8 waves x 400 floats
  int bi = blockIdx.x;
  int J0 = bi*4;
  for (int gidx = threadIdx.x; gidx < 24*384; gidx += 512){
    int ri = gidx / 384;
    int col = (gidx % 384)*8;
    int g = ri >> 2, c = ri & 3;
    const float* p = tl_w + (g*1024 + J0 + c)*3072 + col;
    float4 a = *(const float4*)p;
    float4 b2 = *(const float4*)(p + 4);
    bf16x8 o;
    o[0]=f2bf(a.x); o[1]=f2bf(a.y); o[2]=f2bf(a.z); o[3]=f2bf(a.w);
    o[4]=f2bf(b2.x); o[5]=f2bf(b2.y); o[6]=f2bf(b2.z); o[7]=f2bf(b2.w);
    *(bf16x8*)&WL[ri*3080 + col] = o;
  }
  int lane = threadIdx.x & 63, w = threadIdx.x >> 6;
  int m16 = lane & 15, quad = lane >> 4;
  int uj = J0 + quad;                 // this lane's update channel
  float tb[6];
  #pragma unroll
  for (int g = 0; g < 6; g++) tb[g] = tl_b[g*1024 + uj];
  __syncthreads();
  int phase = 0;
  // prefill HCAT (m-seg = leaf h; leaf/absent child segs)
  int ncnt = NODECNT[0];
  {
    int total = ncnt * 1024;
    for (int idx = bi*512 + threadIdx.x; idx < total; idx += 131072){
      int eid = idx >> 10, j = idx & 1023;
      int e = EINFO[eid]; int b = e >> 8, p = e & 255;
      __hip_atomic_store(&HCAT[eid*3072 + 2048 + j], f2bf(HS[(b*64 + p)*1024 + j]),
                         __ATOMIC_RELAXED, __HIP_MEMORY_SCOPE_AGENT);
      int lq = LCH[b*64 + p];
      if (lq < 0)
        __hip_atomic_store(&HCAT[eid*3072 + j], (short)0, __ATOMIC_RELAXED, __HIP_MEMORY_SCOPE_AGENT);
      else if (!ISNODE[b*64 + lq])
        __hip_atomic_store(&HCAT[eid*3072 + j], f2bf(HS[(b*64 + lq)*1024 + j]),
                           __ATOMIC_RELAXED, __HIP_MEMORY_SCOPE_AGENT);
      int rq = RCH[b*64 + p];
      if (rq < 0)
        __hip_atomic_store(&HCAT[eid*3072 + 1024 + j], (short)0, __ATOMIC_RELAXED, __HIP_MEMORY_SCOPE_AGENT);
      else if (!ISNODE[b*64 + rq])
        __hip_atomic_store(&HCAT[eid*3072 + 1024 + j], f2bf(HS[(b*64 + rq)*1024 + j]),
                           __ATOMIC_RELAXED, __HIP_MEMORY_SCOPE_AGENT);
    }
  }
  treebarS(SLOTS, &phase);
  int maxlev = MAXLEV[0];
  for (int v = 0; v <= maxlev; v++){
    int nc = LEVCNT[v];
    int ntiles = (nc + 15) >> 4;
    for (int nt = w; nt < ntiles; nt += 8){
      int n = nt*16 + m16;
      bool valid = (n < nc);
      int eid = valid ? LEVEID[v*512 + n] : 1023;
      int e   = valid ? LEVLIST[v*512 + n] : 0;
      int b = e >> 8, p = e & 255;
      int lq = valid ? LCH[b*64 + p] : -1;
      int rq = valid ? RCH[b*64 + p] : -1;
      int pr = valid ? PARENTREF[eid] : -1;
      float cl = (valid && lq >= 0) ? CS[(b*64 + lq)*1024 + uj] : 0.f;
      float cr = (valid && rq >= 0) ? CS[(b*64 + rq)*1024 + uj] : 0.f;
      float cm = valid ? CS[(b*64 + p)*1024 + uj] : 0.f;
      const short* bp  = HCAT + eid*3072 + quad*8;
      const short* a0p = WL + m16*3080 + quad*8;
      const short* a1p = WL + (16 + (m16 & 7))*3080 + quad*8;
      f32x4 acc0 = {0,0,0,0}, acc1 = {0,0,0,0};
      // asm-pipelined K-loop: 12 chunks of 8 x 64B loads; chunk c+1 issued
      // before chunk c's MFMAs, vmcnt(8) guarantees chunk c landed while
      // c+1's 8 loads stay in flight.
      i32x4 A[8], B[8];
      #define COMPUTE8(ARR, KB) do { \
        _Pragma("unroll") \
        for (int i = 0; i < 8; i++){ \
          int k0 = (KB) + i*32; \
          bf16x8 ta0 = *(const bf16x8*)(a0p + k0); \
          bf16x8 ta1 = *(const bf16x8*)(a1p + k0); \
          bf16x8 tb_ = *(const bf16x8*)&ARR[i]; \
          acc0 = __builtin_amdgcn_mfma_f32_16x16x32_bf16(ta0, tb_, acc0, 0, 0, 0); \
          acc1 = __builtin_amdgcn_mfma_f32_16x16x32_bf16(ta1, tb_, acc1, 0, 0, 0); \
        } \
      } while(0)
      LOAD8(A, bp);
      #pragma unroll
      for (int kc2 = 0; kc2 < 6; kc2++){
        int c0 = kc2*2;
        LOAD8(B, bp + (c0 + 1)*256);
        WAIT_VM8();
        COMPUTE8(A, c0*256);
        if (c0 + 2 < 12){
          LOAD8(A, bp + (c0 + 2)*256);
          WAIT_VM8();
        } else {
          WAIT_VM0();
        }
        COMPUTE8(B, (c0 + 1)*256);
      }
      #undef COMPUTE8
      // in-wave gate exchange: D row quad*4+r of acc0 = ri (g*4+c) 0..15;
      // acc1 rows map to ri 16+((quad*4+r)&7) (quads 2,3 duplicate 0,1)
      float* ex = EXF + w*400;
      #pragma unroll
      for (int r = 0; r < 4; r++) ex[m16*25 + quad*4 + r] = acc0[r];
      if (quad < 2){
        #pragma unroll
        for (int r = 0; r < 4; r++) ex[m16*25 + 16 + quad*4 + r] = acc1[r];
      }
      // update: lane = (node m16, channel quad)
      if (valid){
        float gv[6];
        #pragma unroll
        for (int g = 0; g < 6; g++) gv[g] = ex[m16*25 + g*4 + quad] + tb[g];
        float c = fsig(gv[1])*cl + fsig(gv[2])*cr + fsig(gv[3])*cm + fsig(gv[0])*ftanh(gv[4]);
        float h = fsig(gv[5])*ftanh(c);
        __hip_atomic_store(&HS[(b*64 + p)*1024 + uj], h, __ATOMIC_RELAXED, __HIP_MEMORY_SCOPE_AGENT);
        __hip_atomic_store(&CS[(b*64 + p)*1024 + uj], c, __ATOMIC_RELAXED, __HIP_MEMORY_SCOPE_AGENT);
        if (pr >= 0)
          __hip_atomic_store(&HCAT[(pr >> 1)*3072 + (pr & 1)*1024 + uj], f2bf(h),
                             __ATOMIC_RELAXED, __HIP_MEMORY_SCOPE_AGENT);
      }
    }
    treebarS(SLOTS, &phase);
  }
  // fused root gather
  for (int idx = bi*512 + threadIdx.x; idx < 32768; idx += 131072){
    int half = idx >> 14;
    int b = (idx >> 10) & 15, j = idx & 1023;
    int rp = ROOTP[b];
    OUT[half*16384 + b*1024 + j] = half ? CS[(b*64 + rp)*1024 + j]
                                        : HS[(b*64 + rp)*1024 + j];
  }
}

extern "C" void kernel_launch(void* const* d_in, const int* in_sizes, int n_in,
                              void* d_out, int out_size, void* d_ws, size_t ws_size,
                              hipStream_t stream) {
  (void)in_sizes; (void)n_in; (void)out_size; (void)ws_size;
  const float* emb    = (const float*)d_in[0];
  const int*   length = (const int*)  d_in[2];
  const float* w_ih   = (const float*)d_in[3];
  const float* w_hh   = (const float*)d_in[4];
  const float* b_ih   = (const float*)d_in[5];
  const float* b_hh   = (const float*)d_in[6];
  const float* tl_w   = (const float*)d_in[7];
  const float* tl_b   = (const float*)d_in[8];
  const float* rk_w1  = (const float*)d_in[9];
  const float* rk_w2  = (const float*)d_in[10];
  float* OUT = (float*)d_out;

  float* ws_f = (float*)d_ws;
  float* GX   = ws_f;                        // 4,194,304 f
  float* HS   = ws_f + 4194304;              // 1,048,576 f
  float* CS   = ws_f + 5242880;              // 1,048,576 f
  short* HCAT = (short*)(ws_f + 6291456);    // 1024*3072 shorts
  float* SC   = ws_f + 7864320;              // 1,024 f
  short* HG   = (short*)(ws_f + 7865344);    // 32,768 shorts
  int*   IW   = (int*)(ws_f + 7881728);
  int* LCH      = IW;               // 1024
  int* RCH      = IW + 1024;        // 1024
  int* ISNODE   = IW + 2048;        // 1024
  int* LEVCNT   = IW + 3072;        // 64
  int* LEVLIST  = IW + 3136;        // 32768
  int* LEVEID   = IW + 35904;       // 32768
  int* EINFO    = IW + 68672;       // 1024
  int* PARENTREF= IW + 69696;       // 1024
  int* ROOTP    = IW + 70720;       // 16
  int* MAXLEV   = IW + 70736;
  int* NODECNT  = IW + 70737;
  int* BAR1     = IW + 70752;       // 32 slots (k_lstm barrier)
  int* GRP      = IW + 70784;       // 256 slots (k_tree3 barrier)

  // bf16 staging copies (transient): live over HS/CS (+HCAT head), which are
  // only written by k_lstm/k_tree3 AFTER k_gx has consumed these.
  short* WIB  = (short*)(ws_f + 4194304);    // 4,194,304 shorts (8MB)
  short* EMBB = (short*)(ws_f + 6291456);    // 1,048,576 shorts (2MB)

  k_prep<<<2560, 256, 0, stream>>>(w_ih, emb, WIB, EMBB);
  k_rank<<<257, 128, 0, stream>>>(emb, rk_w1, rk_w2, SC, HG, LEVCNT, MAXLEV,
                                  NODECNT, BAR1, GRP);
  k_gx<<<1024, 256, 0, stream>>>(WIB, EMBB, b_ih, b_hh, GX);
  k_build<<<16, 64, 0, stream>>>(SC, length, LCH, RCH, ISNODE, LEVCNT, LEVLIST,
                                 LEVEID, EINFO, PARENTREF, NODECNT, ROOTP, MAXLEV, OUT);

  {
    void* args[] = { (void*)&w_hh, (void*)&GX, (void*)&HS, (void*)&CS, (void*)&HG,
                     (void*)&BAR1 };
    hipLaunchCooperativeKernel((const void*)k_lstm, dim3(32), dim3(512), args, 0, stream);
  }
  {
    hipFuncSetAttribute((const void*)k_tree3,
                        hipFuncAttributeMaxDynamicSharedMemorySize, 160640);
    void* args[] = { (void*)&tl_w, (void*)&tl_b, (void*)&HS, (void*)&CS,
                     (void*)&LCH, (void*)&RCH, (void*)&ISNODE,
                     (void*)&LEVCNT, (void*)&LEVLIST, (void*)&LEVEID, (void*)&EINFO,
                     (void*)&PARENTREF, (void*)&NODECNT, (void*)&MAXLEV,
                     (void*)&HCAT, (void*)&ROOTP, (void*)&OUT,
                     (void*)&GRP };
    hipLaunchCooperativeKernel((const void*)k_tree3, dim3(256), dim3(512), args,
                               160640, stream);
  }
}